// Round 1
// baseline (1526.849 us; speedup 1.0000x reference)
//
#include <hip/hip_runtime.h>
#include <hip/hip_bf16.h>
#include <math.h>

// Problem constants (from reference)
#define N_NODES_C 100000
#define E_ORIG    400000
#define E_TOT     500000   // + self loops
#define N_GRAPHS_C 2000
#define KDIM      256      // HEADS*HID = OUT

// ---------------------------------------------------------------------------
// CSR construction (by destination). Graph is identical for all 3 layers.
// ---------------------------------------------------------------------------
__global__ void count_deg_k(const int* __restrict__ ei, int* __restrict__ deg) {
    int e = blockIdx.x * 256 + threadIdx.x;
    if (e >= E_TOT) return;
    int d = (e < E_ORIG) ? ei[E_ORIG + e] : (e - E_ORIG);   // dst row of edge_index, then self loops
    atomicAdd(&deg[d], 1);
}

__global__ void scan_chunk(const int* __restrict__ in, int* __restrict__ out,
                           int* __restrict__ partials, int n) {
    __shared__ int s[256];
    int tid = threadIdx.x;
    int i = blockIdx.x * 256 + tid;
    int v = (i < n) ? in[i] : 0;
    s[tid] = v;
    __syncthreads();
    for (int off = 1; off < 256; off <<= 1) {
        int t = (tid >= off) ? s[tid - off] : 0;
        __syncthreads();
        s[tid] += t;
        __syncthreads();
    }
    if (i < n) out[i] = s[tid] - v;            // exclusive
    if (tid == 255) partials[blockIdx.x] = s[255];
}

__global__ void scan_partials(int* p, int nb) {
    __shared__ int s[512];
    int tid = threadIdx.x;
    int v = (tid < nb) ? p[tid] : 0;
    s[tid] = v;
    __syncthreads();
    for (int off = 1; off < 512; off <<= 1) {
        int t = (tid >= off) ? s[tid - off] : 0;
        __syncthreads();
        s[tid] += t;
        __syncthreads();
    }
    if (tid < nb) p[tid] = s[tid] - v;         // exclusive
}

__global__ void add_partials(int* out, const int* __restrict__ p, int n) {
    int i = blockIdx.x * 256 + threadIdx.x;
    if (i < n) out[i] += p[blockIdx.x];
}

__global__ void scatter_k(const int* __restrict__ ei, const int* __restrict__ rowoff,
                          int* cursor, int* __restrict__ csr_src) {
    int e = blockIdx.x * 256 + threadIdx.x;
    if (e >= E_TOT) return;
    int s, d;
    if (e < E_ORIG) { s = ei[e]; d = ei[E_ORIG + e]; }
    else            { s = e - E_ORIG; d = s; }
    int pos = rowoff[d] + atomicAdd(&cursor[d], 1);
    csr_src[pos] = s;
}

// ---------------------------------------------------------------------------
// GEMM h = X @ W  (X: [N,KIN], W: [KIN,256]) fused with attention dots:
//   ES[n,h] = <h[n,h,:], a_src[h,:]>,  ED likewise.  NH=4 (HID=64) or NH=1.
// 16 nodes per block; 256 threads = 256 output columns.
// ---------------------------------------------------------------------------
template <int KIN, int NH>
__global__ __launch_bounds__(256) void gemm_att(
        const float* __restrict__ X, const float* __restrict__ W,
        const float* __restrict__ ASRC, const float* __restrict__ ADST,
        float* __restrict__ H, float* __restrict__ ES, float* __restrict__ ED) {
    constexpr int NPB = 16;
    __shared__ float xs[NPB][KIN];
    __shared__ float red[2][4];
    int n0 = blockIdx.x * NPB;
    int k = threadIdx.x;

    for (int idx = k; idx < NPB * KIN; idx += 256) {
        int r = idx / KIN, c = idx - r * KIN;
        xs[r][c] = X[(size_t)(n0 + r) * KIN + c];
    }
    __syncthreads();

    float acc[NPB];
#pragma unroll
    for (int r = 0; r < NPB; r++) acc[r] = 0.f;

    for (int i = 0; i < KIN; i++) {
        float w = W[(size_t)i * KDIM + k];
#pragma unroll
        for (int r = 0; r < NPB; r++) acc[r] = fmaf(xs[r][i], w, acc[r]);
    }

    // a_src/a_dst flattened [NH*C] where channel k -> (head=k/C, c=k%C) -> flat k
    float as = ASRC[k];
    float ad = ADST[k];
    int lane = k & 63;
    int wv = k >> 6;                            // wave index == head when NH==4

    for (int r = 0; r < NPB; r++) {
        int n = n0 + r;
        H[(size_t)n * KDIM + k] = acc[r];
        float ps = acc[r] * as;
        float pd = acc[r] * ad;
        for (int off = 32; off; off >>= 1) {
            ps += __shfl_down(ps, off, 64);
            pd += __shfl_down(pd, off, 64);
        }
        if (NH == 4) {
            if (lane == 0) { ES[n * 4 + wv] = ps; ED[n * 4 + wv] = pd; }
        } else {
            if (lane == 0) { red[0][wv] = ps; red[1][wv] = pd; }
            __syncthreads();
            if (k == 0) {
                ES[n] = red[0][0] + red[0][1] + red[0][2] + red[0][3];
                ED[n] = red[1][0] + red[1][1] + red[1][2] + red[1][3];
            }
            __syncthreads();
        }
    }
}

// ---------------------------------------------------------------------------
// Per-dst online-softmax aggregation.
// One block per dst node, 256 threads = 256 channels, head = k/64 (NH=4).
//   e  = leaky_relu(ES[src,h] + ED[dst,h], 0.2)
//   out[dst,k] = (sum_e softmax(e) * H[src,k]) + bias[k]   [+ ReLU]
// ---------------------------------------------------------------------------
template <int NH, bool RELU>
__global__ __launch_bounds__(256) void agg_kernel(
        const float* __restrict__ H, const int* __restrict__ rowoff,
        const int* __restrict__ csr_src, const float* __restrict__ ES,
        const float* __restrict__ ED, const float* __restrict__ bias,
        float* __restrict__ Out) {
    int n = blockIdx.x;
    int k = threadIdx.x;
    int head = (NH == 4) ? (k >> 6) : 0;
    int beg = rowoff[n];
    int end = rowoff[n + 1];
    float edv = ED[n * NH + head];

    float m = -INFINITY, s = 0.f, acc = 0.f;
    for (int j = beg; j < end; j++) {
        int src = csr_src[j];
        float e = ES[src * NH + head] + edv;
        e = (e > 0.f) ? e : 0.2f * e;           // leaky_relu
        float mn = fmaxf(m, e);
        float sc = __expf(m - mn);              // first iter: exp(-inf)=0
        float p  = __expf(e - mn);
        s   = s * sc + p;
        acc = acc * sc + p * H[(size_t)src * KDIM + k];
        m = mn;
    }
    float o = acc / s + bias[k];
    if (RELU) o = fmaxf(o, 0.f);
    Out[(size_t)n * KDIM + k] = o;
}

// ---------------------------------------------------------------------------
// Global max pool over graphs. batch is sorted ascending -> binary search.
// ---------------------------------------------------------------------------
__global__ __launch_bounds__(256) void pool_k(
        const float* __restrict__ O, const int* __restrict__ batch,
        float* __restrict__ out) {
    __shared__ int range[2];
    int g = blockIdx.x, k = threadIdx.x;
    if (k < 2) {
        int v = g + k;
        int lo = 0, hi = N_NODES_C;
        while (lo < hi) { int mid = (lo + hi) >> 1; if (batch[mid] < v) lo = mid + 1; else hi = mid; }
        range[k] = lo;
    }
    __syncthreads();
    float m = -INFINITY;
    for (int i = range[0]; i < range[1]; i++)
        m = fmaxf(m, O[(size_t)i * KDIM + k]);
    out[(size_t)g * KDIM + k] = m;
}

// ---------------------------------------------------------------------------
extern "C" void kernel_launch(void* const* d_in, const int* in_sizes, int n_in,
                              void* d_out, int out_size, void* d_ws, size_t ws_size,
                              hipStream_t stream) {
    const float* x     = (const float*)d_in[0];
    const int*   ei    = (const int*)d_in[1];
    const int*   batch = (const int*)d_in[2];
    const float* W1  = (const float*)d_in[3];
    const float* as1 = (const float*)d_in[4];
    const float* ad1 = (const float*)d_in[5];
    const float* b1  = (const float*)d_in[6];
    const float* W2  = (const float*)d_in[7];
    const float* as2 = (const float*)d_in[8];
    const float* ad2 = (const float*)d_in[9];
    const float* b2  = (const float*)d_in[10];
    const float* W3  = (const float*)d_in[11];
    const float* as3 = (const float*)d_in[12];
    const float* ad3 = (const float*)d_in[13];
    const float* b3  = (const float*)d_in[14];
    float* out = (float*)d_out;

    // Workspace layout (~212 MB)
    char* p = (char*)d_ws;
    auto alloc = [&](size_t bytes) { char* r = p; p += (bytes + 255) & ~(size_t)255; return r; };
    float* buf0   = (float*)alloc((size_t)N_NODES_C * KDIM * 4);
    float* buf1   = (float*)alloc((size_t)N_NODES_C * KDIM * 4);
    float* ES     = (float*)alloc((size_t)N_NODES_C * 4 * 4);
    float* ED     = (float*)alloc((size_t)N_NODES_C * 4 * 4);
    int* deg      = (int*)alloc((N_NODES_C + 1) * 4);
    int* rowoff   = (int*)alloc((N_NODES_C + 1) * 4);
    int* cursor   = (int*)alloc(N_NODES_C * 4);
    int* csr      = (int*)alloc((size_t)E_TOT * 4);
    int* partials = (int*)alloc(512 * 4);

    // --- build CSR (per launch; graph inputs are fixed) ---
    hipMemsetAsync(deg, 0, (N_NODES_C + 1) * 4, stream);
    hipMemsetAsync(cursor, 0, N_NODES_C * 4, stream);
    int egrid = (E_TOT + 255) / 256;
    count_deg_k<<<egrid, 256, 0, stream>>>(ei, deg);
    int nb = (N_NODES_C + 1 + 255) / 256;           // 391
    scan_chunk<<<nb, 256, 0, stream>>>(deg, rowoff, partials, N_NODES_C + 1);
    scan_partials<<<1, 512, 0, stream>>>(partials, nb);
    add_partials<<<nb, 256, 0, stream>>>(rowoff, partials, N_NODES_C + 1);
    scatter_k<<<egrid, 256, 0, stream>>>(ei, rowoff, cursor, csr);

    int ggrid = N_NODES_C / 16;                      // 6250
    // --- layer 1: 58 -> 4x64, relu ---
    gemm_att<58, 4><<<ggrid, 256, 0, stream>>>(x, W1, as1, ad1, buf0, ES, ED);
    agg_kernel<4, true><<<N_NODES_C, 256, 0, stream>>>(buf0, rowoff, csr, ES, ED, b1, buf1);
    // --- layer 2: 256 -> 4x64, relu ---
    gemm_att<256, 4><<<ggrid, 256, 0, stream>>>(buf1, W2, as2, ad2, buf0, ES, ED);
    agg_kernel<4, true><<<N_NODES_C, 256, 0, stream>>>(buf0, rowoff, csr, ES, ED, b2, buf1);
    // --- layer 3: 256 -> 1x256, no relu ---
    gemm_att<256, 1><<<ggrid, 256, 0, stream>>>(buf1, W3, as3, ad3, buf0, ES, ED);
    agg_kernel<1, false><<<N_NODES_C, 256, 0, stream>>>(buf0, rowoff, csr, ES, ED, b3, buf1);
    // --- global max pool ---
    pool_k<<<N_GRAPHS_C, 256, 0, stream>>>(buf1, batch, out);
}

// Round 2
// 981.203 us; speedup vs baseline: 1.5561x; 1.5561x over previous
//
#include <hip/hip_runtime.h>
#include <hip/hip_bf16.h>
#include <math.h>

// Problem constants (from reference)
#define N_NODES_C 100000
#define E_ORIG    400000
#define E_TOT     500000   // + self loops
#define N_GRAPHS_C 2000
#define KDIM      256      // HEADS*HID = OUT

// ---------------------------------------------------------------------------
// CSR construction (by destination). Graph is identical for all 3 layers.
// ---------------------------------------------------------------------------
__global__ void count_deg_k(const int* __restrict__ ei, int* __restrict__ deg) {
    int e = blockIdx.x * 256 + threadIdx.x;
    if (e >= E_TOT) return;
    int d = (e < E_ORIG) ? ei[E_ORIG + e] : (e - E_ORIG);
    atomicAdd(&deg[d], 1);
}

__global__ void scan_chunk(const int* __restrict__ in, int* __restrict__ out,
                           int* __restrict__ partials, int n) {
    __shared__ int s[256];
    int tid = threadIdx.x;
    int i = blockIdx.x * 256 + tid;
    int v = (i < n) ? in[i] : 0;
    s[tid] = v;
    __syncthreads();
    for (int off = 1; off < 256; off <<= 1) {
        int t = (tid >= off) ? s[tid - off] : 0;
        __syncthreads();
        s[tid] += t;
        __syncthreads();
    }
    if (i < n) out[i] = s[tid] - v;            // exclusive
    if (tid == 255) partials[blockIdx.x] = s[255];
}

__global__ void scan_partials(int* p, int nb) {
    __shared__ int s[512];
    int tid = threadIdx.x;
    int v = (tid < nb) ? p[tid] : 0;
    s[tid] = v;
    __syncthreads();
    for (int off = 1; off < 512; off <<= 1) {
        int t = (tid >= off) ? s[tid - off] : 0;
        __syncthreads();
        s[tid] += t;
        __syncthreads();
    }
    if (tid < nb) p[tid] = s[tid] - v;         // exclusive
}

__global__ void add_partials(int* out, const int* __restrict__ p, int n) {
    int i = blockIdx.x * 256 + threadIdx.x;
    if (i < n) out[i] += p[blockIdx.x];
}

__global__ void scatter_k(const int* __restrict__ ei, const int* __restrict__ rowoff,
                          int* cursor, int* __restrict__ csr_src) {
    int e = blockIdx.x * 256 + threadIdx.x;
    if (e >= E_TOT) return;
    int s, d;
    if (e < E_ORIG) { s = ei[e]; d = ei[E_ORIG + e]; }
    else            { s = e - E_ORIG; d = s; }
    int pos = rowoff[d] + atomicAdd(&cursor[d], 1);
    csr_src[pos] = s;
}

// ---------------------------------------------------------------------------
// Register-tiled f32 GEMM h = X @ W (X:[N,KIN], W:[KIN,256]) + attention dots.
// Block: 64 nodes x 256 cols, 256 threads. Wave w owns rows w*16..w*16+15 and
// ALL 256 cols (lane l -> cols 4l..4l+3). Thread tile: 16 rows x 4 cols.
// xs stored transposed [BK][BM+4] so one ds_read_b128 = 4 rows (broadcast,
// conflict-free); W tile staged in LDS (read once per block).
// ---------------------------------------------------------------------------
template <int KIN, int NH>
__global__ __launch_bounds__(256) void gemm_att(
        const float* __restrict__ X, const float* __restrict__ W,
        const float* __restrict__ ASRC, const float* __restrict__ ADST,
        float* __restrict__ H, float* __restrict__ ES, float* __restrict__ ED) {
    constexpr int BM = 64;
    constexpr int BK = (KIN % 32 == 0) ? 32 : KIN;   // 32 for KIN=256; 58 for KIN=58
    constexpr int NT = KIN / BK;
    __shared__ float xs[BK][BM + 4];                 // +4: 16B-aligned rows, conflict-light
    __shared__ float ws[BK][KDIM];

    int n0 = blockIdx.x * BM;
    int t = threadIdx.x;
    int wv = t >> 6;                                 // wave id = row group
    int lane = t & 63;
    int c0 = lane * 4;                               // this thread's 4 columns

    float4 acc[16];
#pragma unroll
    for (int r = 0; r < 16; r++) acc[r] = make_float4(0.f, 0.f, 0.f, 0.f);

    for (int kt = 0; kt < NT; kt++) {
        int k0 = kt * BK;
        // ---- stage X tile (transposed) ----
        if constexpr (KIN % 32 == 0) {
#pragma unroll
            for (int p = 0; p < 2; p++) {
                int r = (t >> 3) + p * 32;
                int i4 = (t & 7) * 4;
                int gr = n0 + r; if (gr >= N_NODES_C) gr = N_NODES_C - 1;
                float4 v = *(const float4*)&X[(size_t)gr * KIN + k0 + i4];
                xs[i4 + 0][r] = v.x; xs[i4 + 1][r] = v.y;
                xs[i4 + 2][r] = v.z; xs[i4 + 3][r] = v.w;
            }
            // ---- stage W tile: BK*64 float4s, 8 per thread ----
#pragma unroll
            for (int p = 0; p < BK * (KDIM / 4) / 256; p++) {
                int idx = t + p * 256;
                int row = idx >> 6, col = (idx & 63) * 4;
                *(float4*)&ws[row][col] = *(const float4*)&W[(size_t)(k0 + row) * KDIM + col];
            }
        } else {
            for (int idx = t; idx < BM * KIN; idx += 256) {
                int r = idx / KIN, i = idx - r * KIN;
                int gr = n0 + r; if (gr >= N_NODES_C) gr = N_NODES_C - 1;
                xs[i][r] = X[(size_t)gr * KIN + i];
            }
            for (int idx = t; idx < KIN * (KDIM / 4); idx += 256) {
                int row = idx >> 6, col = (idx & 63) * 4;
                *(float4*)&ws[row][col] = *(const float4*)&W[(size_t)row * KDIM + col];
            }
        }
        __syncthreads();

#pragma unroll 2
        for (int i = 0; i < BK; i++) {
            float4 b  = *(float4*)&ws[i][c0];
            float4 a0 = *(float4*)&xs[i][wv * 16 + 0];
            float4 a1 = *(float4*)&xs[i][wv * 16 + 4];
            float4 a2 = *(float4*)&xs[i][wv * 16 + 8];
            float4 a3 = *(float4*)&xs[i][wv * 16 + 12];
#define FMA4(r, av) \
            acc[r].x = fmaf(av, b.x, acc[r].x); acc[r].y = fmaf(av, b.y, acc[r].y); \
            acc[r].z = fmaf(av, b.z, acc[r].z); acc[r].w = fmaf(av, b.w, acc[r].w);
            FMA4(0,  a0.x) FMA4(1,  a0.y) FMA4(2,  a0.z) FMA4(3,  a0.w)
            FMA4(4,  a1.x) FMA4(5,  a1.y) FMA4(6,  a1.z) FMA4(7,  a1.w)
            FMA4(8,  a2.x) FMA4(9,  a2.y) FMA4(10, a2.z) FMA4(11, a2.w)
            FMA4(12, a3.x) FMA4(13, a3.y) FMA4(14, a3.z) FMA4(15, a3.w)
#undef FMA4
        }
        __syncthreads();
    }

    // ---- epilogue: H store + attention dots ----
    float4 as4 = *(const float4*)&ASRC[c0];
    float4 ad4 = *(const float4*)&ADST[c0];
    int base = n0 + wv * 16;

#pragma unroll
    for (int r = 0; r < 16; r++) {
        int n = base + r;
        if (n >= N_NODES_C) break;               // wave-uniform
        *(float4*)&H[(size_t)n * KDIM + c0] = acc[r];
        float ps = acc[r].x * as4.x + acc[r].y * as4.y + acc[r].z * as4.z + acc[r].w * as4.w;
        float pd = acc[r].x * ad4.x + acc[r].y * ad4.y + acc[r].z * ad4.z + acc[r].w * ad4.w;
        if (NH == 4) {
            // reduce within 16-lane groups (lane/16 == head)
            for (int off = 8; off; off >>= 1) {
                ps += __shfl_down(ps, off, 16);
                pd += __shfl_down(pd, off, 16);
            }
            if ((lane & 15) == 0) {
                ES[n * 4 + (lane >> 4)] = ps;
                ED[n * 4 + (lane >> 4)] = pd;
            }
        } else {
            for (int off = 32; off; off >>= 1) {
                ps += __shfl_down(ps, off, 64);
                pd += __shfl_down(pd, off, 64);
            }
            if (lane == 0) { ES[n] = ps; ED[n] = pd; }
        }
    }
}

// ---------------------------------------------------------------------------
// Per-dst online-softmax aggregation (unchanged).
// ---------------------------------------------------------------------------
template <int NH, bool RELU>
__global__ __launch_bounds__(256) void agg_kernel(
        const float* __restrict__ H, const int* __restrict__ rowoff,
        const int* __restrict__ csr_src, const float* __restrict__ ES,
        const float* __restrict__ ED, const float* __restrict__ bias,
        float* __restrict__ Out) {
    int n = blockIdx.x;
    int k = threadIdx.x;
    int head = (NH == 4) ? (k >> 6) : 0;
    int beg = rowoff[n];
    int end = rowoff[n + 1];
    float edv = ED[n * NH + head];

    float m = -INFINITY, s = 0.f, acc = 0.f;
    for (int j = beg; j < end; j++) {
        int src = csr_src[j];
        float e = ES[src * NH + head] + edv;
        e = (e > 0.f) ? e : 0.2f * e;           // leaky_relu
        float mn = fmaxf(m, e);
        float sc = __expf(m - mn);              // first iter: exp(-inf)=0
        float p  = __expf(e - mn);
        s   = s * sc + p;
        acc = acc * sc + p * H[(size_t)src * KDIM + k];
        m = mn;
    }
    float o = acc / s + bias[k];
    if (RELU) o = fmaxf(o, 0.f);
    Out[(size_t)n * KDIM + k] = o;
}

// ---------------------------------------------------------------------------
// Global max pool over graphs (unchanged).
// ---------------------------------------------------------------------------
__global__ __launch_bounds__(256) void pool_k(
        const float* __restrict__ O, const int* __restrict__ batch,
        float* __restrict__ out) {
    __shared__ int range[2];
    int g = blockIdx.x, k = threadIdx.x;
    if (k < 2) {
        int v = g + k;
        int lo = 0, hi = N_NODES_C;
        while (lo < hi) { int mid = (lo + hi) >> 1; if (batch[mid] < v) lo = mid + 1; else hi = mid; }
        range[k] = lo;
    }
    __syncthreads();
    float m = -INFINITY;
    for (int i = range[0]; i < range[1]; i++)
        m = fmaxf(m, O[(size_t)i * KDIM + k]);
    out[(size_t)g * KDIM + k] = m;
}

// ---------------------------------------------------------------------------
extern "C" void kernel_launch(void* const* d_in, const int* in_sizes, int n_in,
                              void* d_out, int out_size, void* d_ws, size_t ws_size,
                              hipStream_t stream) {
    const float* x     = (const float*)d_in[0];
    const int*   ei    = (const int*)d_in[1];
    const int*   batch = (const int*)d_in[2];
    const float* W1  = (const float*)d_in[3];
    const float* as1 = (const float*)d_in[4];
    const float* ad1 = (const float*)d_in[5];
    const float* b1  = (const float*)d_in[6];
    const float* W2  = (const float*)d_in[7];
    const float* as2 = (const float*)d_in[8];
    const float* ad2 = (const float*)d_in[9];
    const float* b2  = (const float*)d_in[10];
    const float* W3  = (const float*)d_in[11];
    const float* as3 = (const float*)d_in[12];
    const float* ad3 = (const float*)d_in[13];
    const float* b3  = (const float*)d_in[14];
    float* out = (float*)d_out;

    // Workspace layout (~212 MB)
    char* p = (char*)d_ws;
    auto alloc = [&](size_t bytes) { char* r = p; p += (bytes + 255) & ~(size_t)255; return r; };
    float* buf0   = (float*)alloc((size_t)N_NODES_C * KDIM * 4);
    float* buf1   = (float*)alloc((size_t)N_NODES_C * KDIM * 4);
    float* ES     = (float*)alloc((size_t)N_NODES_C * 4 * 4);
    float* ED     = (float*)alloc((size_t)N_NODES_C * 4 * 4);
    int* deg      = (int*)alloc((N_NODES_C + 1) * 4);
    int* rowoff   = (int*)alloc((N_NODES_C + 1) * 4);
    int* cursor   = (int*)alloc(N_NODES_C * 4);
    int* csr      = (int*)alloc((size_t)E_TOT * 4);
    int* partials = (int*)alloc(512 * 4);

    // --- build CSR ---
    hipMemsetAsync(deg, 0, (N_NODES_C + 1) * 4, stream);
    hipMemsetAsync(cursor, 0, N_NODES_C * 4, stream);
    int egrid = (E_TOT + 255) / 256;
    count_deg_k<<<egrid, 256, 0, stream>>>(ei, deg);
    int nb = (N_NODES_C + 1 + 255) / 256;           // 391
    scan_chunk<<<nb, 256, 0, stream>>>(deg, rowoff, partials, N_NODES_C + 1);
    scan_partials<<<1, 512, 0, stream>>>(partials, nb);
    add_partials<<<nb, 256, 0, stream>>>(rowoff, partials, N_NODES_C + 1);
    scatter_k<<<egrid, 256, 0, stream>>>(ei, rowoff, cursor, csr);

    int ggrid = (N_NODES_C + 63) / 64;               // 1563
    // --- layer 1: 58 -> 4x64, relu ---
    gemm_att<58, 4><<<ggrid, 256, 0, stream>>>(x, W1, as1, ad1, buf0, ES, ED);
    agg_kernel<4, true><<<N_NODES_C, 256, 0, stream>>>(buf0, rowoff, csr, ES, ED, b1, buf1);
    // --- layer 2: 256 -> 4x64, relu ---
    gemm_att<256, 4><<<ggrid, 256, 0, stream>>>(buf1, W2, as2, ad2, buf0, ES, ED);
    agg_kernel<4, true><<<N_NODES_C, 256, 0, stream>>>(buf0, rowoff, csr, ES, ED, b2, buf1);
    // --- layer 3: 256 -> 1x256, no relu ---
    gemm_att<256, 1><<<ggrid, 256, 0, stream>>>(buf1, W3, as3, ad3, buf0, ES, ED);
    agg_kernel<1, false><<<N_NODES_C, 256, 0, stream>>>(buf0, rowoff, csr, ES, ED, b3, buf1);
    // --- global max pool ---
    pool_k<<<N_GRAPHS_C, 256, 0, stream>>>(buf1, batch, out);
}

// Round 3
// 946.301 us; speedup vs baseline: 1.6135x; 1.0369x over previous
//
#include <hip/hip_runtime.h>
#include <hip/hip_bf16.h>
#include <math.h>

// Problem constants (from reference)
#define N_NODES_C 100000
#define E_ORIG    400000
#define E_TOT     500000   // + self loops
#define N_GRAPHS_C 2000
#define KDIM      256      // HEADS*HID = OUT

// ---------------------------------------------------------------------------
// CSR construction (by destination). Graph is identical for all 3 layers.
// ---------------------------------------------------------------------------
__global__ void count_deg_k(const int* __restrict__ ei, int* __restrict__ deg) {
    int e = blockIdx.x * 256 + threadIdx.x;
    if (e >= E_TOT) return;
    int d = (e < E_ORIG) ? ei[E_ORIG + e] : (e - E_ORIG);
    atomicAdd(&deg[d], 1);
}

__global__ void scan_chunk(const int* __restrict__ in, int* __restrict__ out,
                           int* __restrict__ partials, int n) {
    __shared__ int s[256];
    int tid = threadIdx.x;
    int i = blockIdx.x * 256 + tid;
    int v = (i < n) ? in[i] : 0;
    s[tid] = v;
    __syncthreads();
    for (int off = 1; off < 256; off <<= 1) {
        int t = (tid >= off) ? s[tid - off] : 0;
        __syncthreads();
        s[tid] += t;
        __syncthreads();
    }
    if (i < n) out[i] = s[tid] - v;            // exclusive
    if (tid == 255) partials[blockIdx.x] = s[255];
}

__global__ void scan_partials(int* p, int nb) {
    __shared__ int s[512];
    int tid = threadIdx.x;
    int v = (tid < nb) ? p[tid] : 0;
    s[tid] = v;
    __syncthreads();
    for (int off = 1; off < 512; off <<= 1) {
        int t = (tid >= off) ? s[tid - off] : 0;
        __syncthreads();
        s[tid] += t;
        __syncthreads();
    }
    if (tid < nb) p[tid] = s[tid] - v;         // exclusive
}

__global__ void add_partials(int* out, const int* __restrict__ p, int n) {
    int i = blockIdx.x * 256 + threadIdx.x;
    if (i < n) out[i] += p[blockIdx.x];
}

__global__ void scatter_k(const int* __restrict__ ei, const int* __restrict__ rowoff,
                          int* cursor, int* __restrict__ csr_src) {
    int e = blockIdx.x * 256 + threadIdx.x;
    if (e >= E_TOT) return;
    int s, d;
    if (e < E_ORIG) { s = ei[e]; d = ei[E_ORIG + e]; }
    else            { s = e - E_ORIG; d = s; }
    int pos = rowoff[d] + atomicAdd(&cursor[d], 1);
    csr_src[pos] = s;
}

// ---------------------------------------------------------------------------
// Register-tiled f32 GEMM h = X @ W (X:[N,KIN], W:[KIN,256]) + attention dots.
// Block: 64 nodes x 256 cols, 256 threads. Wave w owns rows w*16..w*16+15 and
// ALL 256 cols (lane l -> cols 4l..4l+3). Thread tile: 16 rows x 4 cols.
// Only the X tile is staged in LDS (transposed: [BK][BM+4], b128 broadcast
// reads). W is streamed straight from L2 inside the FMA loop (every block
// reads the same 256 KB -> L2-resident; staging it in LDS was pure overhead).
// Next X tile is prefetched into registers during compute (T14-style split).
// ---------------------------------------------------------------------------
template <int KIN, int NH>
__global__ __launch_bounds__(256) void gemm_att(
        const float* __restrict__ X, const float* __restrict__ W,
        const float* __restrict__ ASRC, const float* __restrict__ ADST,
        float* __restrict__ H, float* __restrict__ ES, float* __restrict__ ED) {
    constexpr int BM = 64;
    constexpr int BK = (KIN % 64 == 0) ? 64 : KIN;   // 64 for KIN=256; 58 for KIN=58
    constexpr int NT = KIN / BK;
    __shared__ float xs[BK][BM + 4];

    int n0 = blockIdx.x * BM;
    int t = threadIdx.x;
    int wv = t >> 6;
    int lane = t & 63;
    int c0 = lane * 4;

    float4 acc[16];
#pragma unroll
    for (int r = 0; r < 16; r++) acc[r] = make_float4(0.f, 0.f, 0.f, 0.f);

    // staging pattern (KIN%64==0): thread t loads rows (t>>4)+16p, k-quad t&15
    int kq = t & 15;
    int rbase = t >> 4;
    float4 xreg[4];

    auto load_x = [&](int kt) {
        if constexpr (KIN % 64 == 0) {
#pragma unroll
            for (int p = 0; p < 4; p++) {
                int gr = n0 + rbase + 16 * p;
                if (gr >= N_NODES_C) gr = N_NODES_C - 1;
                xreg[p] = *(const float4*)&X[(size_t)gr * KIN + kt * BK + kq * 4];
            }
        }
    };

    if constexpr (KIN % 64 == 0) {
        load_x(0);
        for (int kt = 0; kt < NT; kt++) {
            __syncthreads();                      // prev tile fully consumed
#pragma unroll
            for (int p = 0; p < 4; p++) {
                xs[kq * 4 + 0][rbase + 16 * p] = xreg[p].x;
                xs[kq * 4 + 1][rbase + 16 * p] = xreg[p].y;
                xs[kq * 4 + 2][rbase + 16 * p] = xreg[p].z;
                xs[kq * 4 + 3][rbase + 16 * p] = xreg[p].w;
            }
            __syncthreads();
            if (kt + 1 < NT) load_x(kt + 1);      // overlaps with compute below

            const float* __restrict__ Wk = W + (size_t)kt * BK * KDIM + c0;
#pragma unroll 4
            for (int i = 0; i < BK; i++) {
                float4 b  = *(const float4*)&Wk[(size_t)i * KDIM];
                float4 a0 = *(float4*)&xs[i][wv * 16 + 0];
                float4 a1 = *(float4*)&xs[i][wv * 16 + 4];
                float4 a2 = *(float4*)&xs[i][wv * 16 + 8];
                float4 a3 = *(float4*)&xs[i][wv * 16 + 12];
#define FMA4(r, av) \
                acc[r].x = fmaf(av, b.x, acc[r].x); acc[r].y = fmaf(av, b.y, acc[r].y); \
                acc[r].z = fmaf(av, b.z, acc[r].z); acc[r].w = fmaf(av, b.w, acc[r].w);
                FMA4(0,  a0.x) FMA4(1,  a0.y) FMA4(2,  a0.z) FMA4(3,  a0.w)
                FMA4(4,  a1.x) FMA4(5,  a1.y) FMA4(6,  a1.z) FMA4(7,  a1.w)
                FMA4(8,  a2.x) FMA4(9,  a2.y) FMA4(10, a2.z) FMA4(11, a2.w)
                FMA4(12, a3.x) FMA4(13, a3.y) FMA4(14, a3.z) FMA4(15, a3.w)
            }
        }
    } else {
        // KIN=58 path: single tile, simple staging
        for (int idx = t; idx < BM * KIN; idx += 256) {
            int i = idx % KIN, r = idx / KIN;
            int gr = n0 + r; if (gr >= N_NODES_C) gr = N_NODES_C - 1;
            xs[i][r] = X[(size_t)gr * KIN + i];
        }
        __syncthreads();
        const float* __restrict__ Wk = W + c0;
#pragma unroll 2
        for (int i = 0; i < BK; i++) {
            float4 b  = *(const float4*)&Wk[(size_t)i * KDIM];
            float4 a0 = *(float4*)&xs[i][wv * 16 + 0];
            float4 a1 = *(float4*)&xs[i][wv * 16 + 4];
            float4 a2 = *(float4*)&xs[i][wv * 16 + 8];
            float4 a3 = *(float4*)&xs[i][wv * 16 + 12];
            FMA4(0,  a0.x) FMA4(1,  a0.y) FMA4(2,  a0.z) FMA4(3,  a0.w)
            FMA4(4,  a1.x) FMA4(5,  a1.y) FMA4(6,  a1.z) FMA4(7,  a1.w)
            FMA4(8,  a2.x) FMA4(9,  a2.y) FMA4(10, a2.z) FMA4(11, a2.w)
            FMA4(12, a3.x) FMA4(13, a3.y) FMA4(14, a3.z) FMA4(15, a3.w)
#undef FMA4
        }
    }

    // ---- epilogue: H store + attention dots ----
    float4 as4 = *(const float4*)&ASRC[c0];
    float4 ad4 = *(const float4*)&ADST[c0];
    int base = n0 + wv * 16;

#pragma unroll
    for (int r = 0; r < 16; r++) {
        int n = base + r;
        if (n >= N_NODES_C) break;               // wave-uniform
        *(float4*)&H[(size_t)n * KDIM + c0] = acc[r];
        float ps = acc[r].x * as4.x + acc[r].y * as4.y + acc[r].z * as4.z + acc[r].w * as4.w;
        float pd = acc[r].x * ad4.x + acc[r].y * ad4.y + acc[r].z * ad4.z + acc[r].w * ad4.w;
        if (NH == 4) {
            for (int off = 8; off; off >>= 1) {
                ps += __shfl_down(ps, off, 16);
                pd += __shfl_down(pd, off, 16);
            }
            if ((lane & 15) == 0) {
                ES[n * 4 + (lane >> 4)] = ps;
                ED[n * 4 + (lane >> 4)] = pd;
            }
        } else {
            for (int off = 32; off; off >>= 1) {
                ps += __shfl_down(ps, off, 64);
                pd += __shfl_down(pd, off, 64);
            }
            if (lane == 0) { ES[n] = ps; ED[n] = pd; }
        }
    }
}

// ---------------------------------------------------------------------------
// Per-dst softmax aggregation: one WAVE per node (4 nodes/block), lane owns
// 4 channels (float4 gather -> coalesced 1KB row per wave). Two-pass softmax:
// pass 1 max over cheap ES loads, pass 2 accumulates exp(e-m)*H with
// address-independent gathers (full MLP, no serial rescale chain).
// ---------------------------------------------------------------------------
template <int NH, bool RELU>
__global__ __launch_bounds__(256) void agg_kernel(
        const float* __restrict__ H, const int* __restrict__ rowoff,
        const int* __restrict__ csr_src, const float* __restrict__ ES,
        const float* __restrict__ ED, const float* __restrict__ bias,
        float* __restrict__ Out) {
    int node = blockIdx.x * 4 + (threadIdx.x >> 6);
    if (node >= N_NODES_C) return;
    int lane = threadIdx.x & 63;
    int c0 = lane * 4;
    int head = (NH == 4) ? (lane >> 4) : 0;
    int beg = rowoff[node];
    int end = rowoff[node + 1];
    float edv = ED[node * NH + head];

    float m = -1e30f;
    for (int j = beg; j < end; j++) {
        float e = ES[csr_src[j] * NH + head] + edv;
        e = (e > 0.f) ? e : 0.2f * e;
        m = fmaxf(m, e);
    }
    float s = 0.f;
    float4 acc = make_float4(0.f, 0.f, 0.f, 0.f);
    for (int j = beg; j < end; j++) {
        int src = csr_src[j];
        float e = ES[src * NH + head] + edv;
        e = (e > 0.f) ? e : 0.2f * e;
        float p = __expf(e - m);
        s += p;
        float4 h = *(const float4*)&H[(size_t)src * KDIM + c0];
        acc.x = fmaf(p, h.x, acc.x);
        acc.y = fmaf(p, h.y, acc.y);
        acc.z = fmaf(p, h.z, acc.z);
        acc.w = fmaf(p, h.w, acc.w);
    }
    float inv = 1.f / s;
    float4 b4 = *(const float4*)&bias[c0];
    float4 o;
    o.x = fmaf(acc.x, inv, b4.x);
    o.y = fmaf(acc.y, inv, b4.y);
    o.z = fmaf(acc.z, inv, b4.z);
    o.w = fmaf(acc.w, inv, b4.w);
    if (RELU) {
        o.x = fmaxf(o.x, 0.f); o.y = fmaxf(o.y, 0.f);
        o.z = fmaxf(o.z, 0.f); o.w = fmaxf(o.w, 0.f);
    }
    *(float4*)&Out[(size_t)node * KDIM + c0] = o;
}

// ---------------------------------------------------------------------------
// Global max pool over graphs. batch is sorted ascending -> binary search.
// ---------------------------------------------------------------------------
__global__ __launch_bounds__(256) void pool_k(
        const float* __restrict__ O, const int* __restrict__ batch,
        float* __restrict__ out) {
    __shared__ int range[2];
    int g = blockIdx.x, k = threadIdx.x;
    if (k < 2) {
        int v = g + k;
        int lo = 0, hi = N_NODES_C;
        while (lo < hi) { int mid = (lo + hi) >> 1; if (batch[mid] < v) lo = mid + 1; else hi = mid; }
        range[k] = lo;
    }
    __syncthreads();
    float m = -INFINITY;
    for (int i = range[0]; i < range[1]; i++)
        m = fmaxf(m, O[(size_t)i * KDIM + k]);
    out[(size_t)g * KDIM + k] = m;
}

// ---------------------------------------------------------------------------
extern "C" void kernel_launch(void* const* d_in, const int* in_sizes, int n_in,
                              void* d_out, int out_size, void* d_ws, size_t ws_size,
                              hipStream_t stream) {
    const float* x     = (const float*)d_in[0];
    const int*   ei    = (const int*)d_in[1];
    const int*   batch = (const int*)d_in[2];
    const float* W1  = (const float*)d_in[3];
    const float* as1 = (const float*)d_in[4];
    const float* ad1 = (const float*)d_in[5];
    const float* b1  = (const float*)d_in[6];
    const float* W2  = (const float*)d_in[7];
    const float* as2 = (const float*)d_in[8];
    const float* ad2 = (const float*)d_in[9];
    const float* b2  = (const float*)d_in[10];
    const float* W3  = (const float*)d_in[11];
    const float* as3 = (const float*)d_in[12];
    const float* ad3 = (const float*)d_in[13];
    const float* b3  = (const float*)d_in[14];
    float* out = (float*)d_out;

    // Workspace layout (~212 MB)
    char* p = (char*)d_ws;
    auto alloc = [&](size_t bytes) { char* r = p; p += (bytes + 255) & ~(size_t)255; return r; };
    float* buf0   = (float*)alloc((size_t)N_NODES_C * KDIM * 4);
    float* buf1   = (float*)alloc((size_t)N_NODES_C * KDIM * 4);
    float* ES     = (float*)alloc((size_t)N_NODES_C * 4 * 4);
    float* ED     = (float*)alloc((size_t)N_NODES_C * 4 * 4);
    int* deg      = (int*)alloc((N_NODES_C + 1) * 4);
    int* rowoff   = (int*)alloc((N_NODES_C + 1) * 4);
    int* cursor   = (int*)alloc(N_NODES_C * 4);
    int* csr      = (int*)alloc((size_t)E_TOT * 4);
    int* partials = (int*)alloc(512 * 4);

    // --- build CSR ---
    hipMemsetAsync(deg, 0, (N_NODES_C + 1) * 4, stream);
    hipMemsetAsync(cursor, 0, N_NODES_C * 4, stream);
    int egrid = (E_TOT + 255) / 256;
    count_deg_k<<<egrid, 256, 0, stream>>>(ei, deg);
    int nb = (N_NODES_C + 1 + 255) / 256;           // 391
    scan_chunk<<<nb, 256, 0, stream>>>(deg, rowoff, partials, N_NODES_C + 1);
    scan_partials<<<1, 512, 0, stream>>>(partials, nb);
    add_partials<<<nb, 256, 0, stream>>>(rowoff, partials, N_NODES_C + 1);
    scatter_k<<<egrid, 256, 0, stream>>>(ei, rowoff, cursor, csr);

    int ggrid = (N_NODES_C + 63) / 64;               // 1563
    int agrid = (N_NODES_C + 3) / 4;                 // 25000
    // --- layer 1: 58 -> 4x64, relu ---
    gemm_att<58, 4><<<ggrid, 256, 0, stream>>>(x, W1, as1, ad1, buf0, ES, ED);
    agg_kernel<4, true><<<agrid, 256, 0, stream>>>(buf0, rowoff, csr, ES, ED, b1, buf1);
    // --- layer 2: 256 -> 4x64, relu ---
    gemm_att<256, 4><<<ggrid, 256, 0, stream>>>(buf1, W2, as2, ad2, buf0, ES, ED);
    agg_kernel<4, true><<<agrid, 256, 0, stream>>>(buf0, rowoff, csr, ES, ED, b2, buf1);
    // --- layer 3: 256 -> 1x256, no relu ---
    gemm_att<256, 1><<<ggrid, 256, 0, stream>>>(buf1, W3, as3, ad3, buf0, ES, ED);
    agg_kernel<1, false><<<agrid, 256, 0, stream>>>(buf0, rowoff, csr, ES, ED, b3, buf1);
    // --- global max pool ---
    pool_k<<<N_GRAPHS_C, 256, 0, stream>>>(buf1, batch, out);
}

// Round 4
// 481.498 us; speedup vs baseline: 3.1710x; 1.9653x over previous
//
#include <hip/hip_runtime.h>
#include <hip/hip_bf16.h>
#include <math.h>

// Problem constants (from reference)
#define N_NODES_C 100000
#define E_ORIG    400000
#define E_TOT     500000   // + self loops
#define N_GRAPHS_C 2000
#define KDIM      256      // HEADS*HID = OUT

typedef __attribute__((ext_vector_type(8))) short short8v;  // 8 bf16 = 4 VGPR
typedef __attribute__((ext_vector_type(4))) float f32x4;

__device__ __forceinline__ void gload_lds16(const void* g, void* l) {
    __builtin_amdgcn_global_load_lds(
        (const __attribute__((address_space(1))) unsigned int*)g,
        (__attribute__((address_space(3))) unsigned int*)l, 16, 0, 0);
}

__device__ __forceinline__ float bflo(unsigned u) { return __uint_as_float(u << 16); }
__device__ __forceinline__ float bfhi(unsigned u) { return __uint_as_float(u & 0xffff0000u); }

// ---------------------------------------------------------------------------
// CSR construction (by destination). Graph is identical for all 3 layers.
// ---------------------------------------------------------------------------
__global__ void count_deg_k(const int* __restrict__ ei, int* __restrict__ deg) {
    int e = blockIdx.x * 256 + threadIdx.x;
    if (e >= E_TOT) return;
    int d = (e < E_ORIG) ? ei[E_ORIG + e] : (e - E_ORIG);
    atomicAdd(&deg[d], 1);
}

__global__ void scan_chunk(const int* __restrict__ in, int* __restrict__ out,
                           int* __restrict__ partials, int n) {
    __shared__ int s[256];
    int tid = threadIdx.x;
    int i = blockIdx.x * 256 + tid;
    int v = (i < n) ? in[i] : 0;
    s[tid] = v;
    __syncthreads();
    for (int off = 1; off < 256; off <<= 1) {
        int t = (tid >= off) ? s[tid - off] : 0;
        __syncthreads();
        s[tid] += t;
        __syncthreads();
    }
    if (i < n) out[i] = s[tid] - v;            // exclusive
    if (tid == 255) partials[blockIdx.x] = s[255];
}

__global__ void scan_partials(int* p, int nb) {
    __shared__ int s[512];
    int tid = threadIdx.x;
    int v = (tid < nb) ? p[tid] : 0;
    s[tid] = v;
    __syncthreads();
    for (int off = 1; off < 512; off <<= 1) {
        int t = (tid >= off) ? s[tid - off] : 0;
        __syncthreads();
        s[tid] += t;
        __syncthreads();
    }
    if (tid < nb) p[tid] = s[tid] - v;         // exclusive
}

__global__ void add_partials(int* out, const int* __restrict__ p, int n) {
    int i = blockIdx.x * 256 + threadIdx.x;
    if (i < n) out[i] += p[blockIdx.x];
}

__global__ void scatter_k(const int* __restrict__ ei, const int* __restrict__ rowoff,
                          int* cursor, int* __restrict__ csr_src) {
    int e = blockIdx.x * 256 + threadIdx.x;
    if (e >= E_TOT) return;
    int s, d;
    if (e < E_ORIG) { s = ei[e]; d = ei[E_ORIG + e]; }
    else            { s = e - E_ORIG; d = s; }
    int pos = rowoff[d] + atomicAdd(&cursor[d], 1);
    csr_src[pos] = s;
}

// ---------------------------------------------------------------------------
// Input conversions to bf16.
// ---------------------------------------------------------------------------
__global__ void conv_x_k(const float* __restrict__ x, __hip_bfloat16* __restrict__ Xb) {
    int idx = blockIdx.x * 256 + threadIdx.x;          // N*64 total
    if (idx >= N_NODES_C * 64) return;
    int row = idx >> 6, c = idx & 63;
    float v = (c < 58) ? x[row * 58 + c] : 0.f;
    Xb[idx] = __float2bfloat16(v);
}

// Wt[c][kpad] = W[k][c] (zero-padded in k)
template <int K, int KPAD>
__global__ void conv_wt_k(const float* __restrict__ W, __hip_bfloat16* __restrict__ Wt) {
    int idx = blockIdx.x * 256 + threadIdx.x;          // 256*KPAD total
    if (idx >= 256 * KPAD) return;
    int c = idx / KPAD, k = idx - c * KPAD;
    float v = (k < K) ? W[k * 256 + c] : 0.f;
    Wt[idx] = __float2bfloat16(v);
}

// ---------------------------------------------------------------------------
// MFMA bf16 GEMM: H = X @ W  (X:[N][KPAD] bf16, Wt:[256 cols][KPAD] bf16)
// + fused attention dots ES/ED.
// Block: 64 rows x 256 cols, 4 waves (wr=wv>>1 rows, wc=wv&1 col-half).
// Wave tile 32x128 = 2x8 fragments of 16x16, mfma_f32_16x16x32_bf16.
// LDS tiles [idx][64k] bf16 (128B rows) with chunk-XOR swizzle (q ^= row&7):
// staged via global_load_lds (linear dest, pre-swizzled global source),
// read via swizzled ds_read_b128 -> 2-way conflicts only (free).
// ---------------------------------------------------------------------------
template <int KPAD, int NH>
__global__ __launch_bounds__(256) void gemm_mfma(
        const __hip_bfloat16* __restrict__ Xb, const __hip_bfloat16* __restrict__ Wt,
        const float* __restrict__ ASRC, const float* __restrict__ ADST,
        __hip_bfloat16* __restrict__ H, float* __restrict__ ES, float* __restrict__ ED) {
    __shared__ char As[64 * 128];                    // [64 rows][64 k] bf16
    __shared__ char Bs[256 * 128];                   // [256 cols][64 k] bf16
    __shared__ float red[2][64][2];                  // NH==1 cross-wave ES/ED

    const int t = threadIdx.x;
    const int wv = t >> 6, lane = t & 63;
    const int wr = wv >> 1, wc = wv & 1;
    const int r15 = lane & 15, hi = lane >> 4;
    const int n0 = blockIdx.x * 64;
    const int srow = lane >> 3;                      // staging: row-within-8
    const int sx = ((lane & 7) ^ srow) * 16;         // pre-swizzled source chunk
    constexpr int KB = KPAD * 2;                     // row bytes

    f32x4 acc[2][8];
#pragma unroll
    for (int m = 0; m < 2; m++)
#pragma unroll
        for (int n = 0; n < 8; n++) acc[m][n] = (f32x4){0.f, 0.f, 0.f, 0.f};

    for (int kt = 0; kt < KPAD / 64; kt++) {
        if (kt) __syncthreads();
        const int k0b = kt * 128;
        // ---- stage A: 8 x 1KB instructions (2 per wave) ----
#pragma unroll
        for (int p = 0; p < 2; p++) {
            int i = wv * 2 + p;
            int gr = n0 + i * 8 + srow;
            if (gr > N_NODES_C - 1) gr = N_NODES_C - 1;
            gload_lds16((const char*)Xb + (size_t)gr * KB + k0b + sx, As + i * 1024);
        }
        // ---- stage B: 32 x 1KB (8 per wave) ----
#pragma unroll
        for (int p = 0; p < 8; p++) {
            int i = wv * 8 + p;
            int col = i * 8 + srow;
            gload_lds16((const char*)Wt + (size_t)col * KB + k0b + sx, Bs + i * 1024);
        }
        asm volatile("s_waitcnt vmcnt(0)" ::: "memory");
        __syncthreads();

        // ---- compute: 2 k-substeps of 32 ----
#pragma unroll
        for (int ks = 0; ks < 2; ks++) {
            const int cx = ((ks * 4 + hi) ^ (r15 & 7)) * 16;  // swizzled chunk byte
            short8v a0 = *(const short8v*)(As + (wr * 32 + 0  + r15) * 128 + cx);
            short8v a1 = *(const short8v*)(As + (wr * 32 + 16 + r15) * 128 + cx);
            short8v b[8];
#pragma unroll
            for (int n = 0; n < 8; n++)
                b[n] = *(const short8v*)(Bs + (wc * 128 + n * 16 + r15) * 128 + cx);
#pragma unroll
            for (int n = 0; n < 8; n++) {
                acc[0][n] = __builtin_amdgcn_mfma_f32_16x16x32_bf16(a0, b[n], acc[0][n], 0, 0, 0);
                acc[1][n] = __builtin_amdgcn_mfma_f32_16x16x32_bf16(a1, b[n], acc[1][n], 0, 0, 0);
            }
        }
    }

    // ---- epilogue: H (bf16) + attention dots ----
    float asv[8], adv[8];
#pragma unroll
    for (int n = 0; n < 8; n++) {
        int col = wc * 128 + n * 16 + r15;
        asv[n] = ASRC[col];
        adv[n] = ADST[col];
    }

#pragma unroll
    for (int m = 0; m < 2; m++) {
#pragma unroll
        for (int j = 0; j < 4; j++) {
            int lrow = wr * 32 + m * 16 + hi * 4 + j;
            int row = n0 + lrow;
            bool ok = row < N_NODES_C;
            if (ok) {
#pragma unroll
                for (int n = 0; n < 8; n++)
                    H[(size_t)row * KDIM + wc * 128 + n * 16 + r15] =
                        __float2bfloat16(acc[m][n][j]);
            }
            if (NH == 4) {
                float p0s = 0.f, p1s = 0.f, p0d = 0.f, p1d = 0.f;
#pragma unroll
                for (int n = 0; n < 4; n++) {
                    p0s = fmaf(acc[m][n][j], asv[n], p0s);
                    p0d = fmaf(acc[m][n][j], adv[n], p0d);
                    p1s = fmaf(acc[m][n + 4][j], asv[n + 4], p1s);
                    p1d = fmaf(acc[m][n + 4][j], adv[n + 4], p1d);
                }
#pragma unroll
                for (int s = 8; s; s >>= 1) {
                    p0s += __shfl_xor(p0s, s, 16);
                    p0d += __shfl_xor(p0d, s, 16);
                    p1s += __shfl_xor(p1s, s, 16);
                    p1d += __shfl_xor(p1d, s, 16);
                }
                if (r15 == 0 && ok) {
                    ES[row * 4 + wc * 2 + 0] = p0s;
                    ES[row * 4 + wc * 2 + 1] = p1s;
                    ED[row * 4 + wc * 2 + 0] = p0d;
                    ED[row * 4 + wc * 2 + 1] = p1d;
                }
            } else {
                float ps = 0.f, pd = 0.f;
#pragma unroll
                for (int n = 0; n < 8; n++) {
                    ps = fmaf(acc[m][n][j], asv[n], ps);
                    pd = fmaf(acc[m][n][j], adv[n], pd);
                }
#pragma unroll
                for (int s = 8; s; s >>= 1) {
                    ps += __shfl_xor(ps, s, 16);
                    pd += __shfl_xor(pd, s, 16);
                }
                if (r15 == 0) { red[0][lrow][wc] = ps; red[1][lrow][wc] = pd; }
            }
        }
    }
    if (NH == 1) {
        __syncthreads();
        if (t < 64) {
            int row = n0 + t;
            if (row < N_NODES_C) {
                ES[row] = red[0][t][0] + red[0][t][1];
                ED[row] = red[1][t][0] + red[1][t][1];
            }
        }
    }
}

// ---------------------------------------------------------------------------
// Per-dst softmax aggregation: one wave per node, lane owns 4 channels
// (8B bf16 gathers). Two-pass softmax; bf16 in, bf16 out (bias+optional ReLU
// applied in f32 before rounding).
// ---------------------------------------------------------------------------
template <int NH, bool RELU>
__global__ __launch_bounds__(256) void agg_kernel(
        const __hip_bfloat16* __restrict__ H, const int* __restrict__ rowoff,
        const int* __restrict__ csr_src, const float* __restrict__ ES,
        const float* __restrict__ ED, const float* __restrict__ bias,
        __hip_bfloat16* __restrict__ Out) {
    int node = blockIdx.x * 4 + (threadIdx.x >> 6);
    if (node >= N_NODES_C) return;
    int lane = threadIdx.x & 63;
    int c0 = lane * 4;
    int head = (NH == 4) ? (lane >> 4) : 0;
    int beg = rowoff[node];
    int end = rowoff[node + 1];
    float edv = ED[node * NH + head];

    float m = -1e30f;
    for (int j = beg; j < end; j++) {
        float e = ES[csr_src[j] * NH + head] + edv;
        e = (e > 0.f) ? e : 0.2f * e;
        m = fmaxf(m, e);
    }
    float s = 0.f;
    float a0 = 0.f, a1 = 0.f, a2 = 0.f, a3 = 0.f;
    const unsigned short* Hu = (const unsigned short*)H;
    for (int j = beg; j < end; j++) {
        int src = csr_src[j];
        float e = ES[src * NH + head] + edv;
        e = (e > 0.f) ? e : 0.2f * e;
        float p = __expf(e - m);
        s += p;
        uint2 v = *(const uint2*)(Hu + (size_t)src * KDIM + c0);
        a0 = fmaf(p, bflo(v.x), a0);
        a1 = fmaf(p, bfhi(v.x), a1);
        a2 = fmaf(p, bflo(v.y), a2);
        a3 = fmaf(p, bfhi(v.y), a3);
    }
    float inv = 1.f / s;
    float o0 = fmaf(a0, inv, bias[c0 + 0]);
    float o1 = fmaf(a1, inv, bias[c0 + 1]);
    float o2 = fmaf(a2, inv, bias[c0 + 2]);
    float o3 = fmaf(a3, inv, bias[c0 + 3]);
    if (RELU) {
        o0 = fmaxf(o0, 0.f); o1 = fmaxf(o1, 0.f);
        o2 = fmaxf(o2, 0.f); o3 = fmaxf(o3, 0.f);
    }
    size_t ob = (size_t)node * KDIM + c0;
    Out[ob + 0] = __float2bfloat16(o0);
    Out[ob + 1] = __float2bfloat16(o1);
    Out[ob + 2] = __float2bfloat16(o2);
    Out[ob + 3] = __float2bfloat16(o3);
}

// ---------------------------------------------------------------------------
// Global max pool over graphs (bf16 input, f32 output).
// ---------------------------------------------------------------------------
__global__ __launch_bounds__(256) void pool_k(
        const __hip_bfloat16* __restrict__ O, const int* __restrict__ batch,
        float* __restrict__ out) {
    __shared__ int range[2];
    int g = blockIdx.x, k = threadIdx.x;
    if (k < 2) {
        int v = g + k;
        int lo = 0, hi = N_NODES_C;
        while (lo < hi) { int mid = (lo + hi) >> 1; if (batch[mid] < v) lo = mid + 1; else hi = mid; }
        range[k] = lo;
    }
    __syncthreads();
    float m = -INFINITY;
    for (int i = range[0]; i < range[1]; i++)
        m = fmaxf(m, __bfloat162float(O[(size_t)i * KDIM + k]));
    out[(size_t)g * KDIM + k] = m;
}

// ---------------------------------------------------------------------------
extern "C" void kernel_launch(void* const* d_in, const int* in_sizes, int n_in,
                              void* d_out, int out_size, void* d_ws, size_t ws_size,
                              hipStream_t stream) {
    const float* x     = (const float*)d_in[0];
    const int*   ei    = (const int*)d_in[1];
    const int*   batch = (const int*)d_in[2];
    const float* W1  = (const float*)d_in[3];
    const float* as1 = (const float*)d_in[4];
    const float* ad1 = (const float*)d_in[5];
    const float* b1  = (const float*)d_in[6];
    const float* W2  = (const float*)d_in[7];
    const float* as2 = (const float*)d_in[8];
    const float* ad2 = (const float*)d_in[9];
    const float* b2  = (const float*)d_in[10];
    const float* W3  = (const float*)d_in[11];
    const float* as3 = (const float*)d_in[12];
    const float* ad3 = (const float*)d_in[13];
    const float* b3  = (const float*)d_in[14];
    float* out = (float*)d_out;

    // Workspace layout (~121 MB)
    char* p = (char*)d_ws;
    auto alloc = [&](size_t bytes) { char* r = p; p += (bytes + 255) & ~(size_t)255; return r; };
    __hip_bfloat16* Xb  = (__hip_bfloat16*)alloc((size_t)N_NODES_C * 64 * 2);
    __hip_bfloat16* Hb  = (__hip_bfloat16*)alloc((size_t)N_NODES_C * KDIM * 2);
    __hip_bfloat16* Nb  = (__hip_bfloat16*)alloc((size_t)N_NODES_C * KDIM * 2);
    __hip_bfloat16* Wt1 = (__hip_bfloat16*)alloc(256 * 64 * 2);
    __hip_bfloat16* Wt2 = (__hip_bfloat16*)alloc(256 * 256 * 2);
    __hip_bfloat16* Wt3 = (__hip_bfloat16*)alloc(256 * 256 * 2);
    float* ES     = (float*)alloc((size_t)N_NODES_C * 4 * 4);
    float* ED     = (float*)alloc((size_t)N_NODES_C * 4 * 4);
    int* deg      = (int*)alloc((N_NODES_C + 1) * 4);
    int* rowoff   = (int*)alloc((N_NODES_C + 1) * 4);
    int* cursor   = (int*)alloc(N_NODES_C * 4);
    int* csr      = (int*)alloc((size_t)E_TOT * 4);
    int* partials = (int*)alloc(512 * 4);

    // --- input conversions ---
    conv_x_k<<<(N_NODES_C * 64 + 255) / 256, 256, 0, stream>>>(x, Xb);
    conv_wt_k<58, 64><<<64, 256, 0, stream>>>(W1, Wt1);
    conv_wt_k<256, 256><<<256, 256, 0, stream>>>(W2, Wt2);
    conv_wt_k<256, 256><<<256, 256, 0, stream>>>(W3, Wt3);

    // --- build CSR ---
    hipMemsetAsync(deg, 0, (N_NODES_C + 1) * 4, stream);
    hipMemsetAsync(cursor, 0, N_NODES_C * 4, stream);
    int egrid = (E_TOT + 255) / 256;
    count_deg_k<<<egrid, 256, 0, stream>>>(ei, deg);
    int nb = (N_NODES_C + 1 + 255) / 256;           // 391
    scan_chunk<<<nb, 256, 0, stream>>>(deg, rowoff, partials, N_NODES_C + 1);
    scan_partials<<<1, 512, 0, stream>>>(partials, nb);
    add_partials<<<nb, 256, 0, stream>>>(rowoff, partials, N_NODES_C + 1);
    scatter_k<<<egrid, 256, 0, stream>>>(ei, rowoff, cursor, csr);

    int ggrid = (N_NODES_C + 63) / 64;               // 1563
    int agrid = (N_NODES_C + 3) / 4;                 // 25000
    // --- layer 1: 58(->64) -> 4x64, relu ---
    gemm_mfma<64, 4><<<ggrid, 256, 0, stream>>>(Xb, Wt1, as1, ad1, Hb, ES, ED);
    agg_kernel<4, true><<<agrid, 256, 0, stream>>>(Hb, rowoff, csr, ES, ED, b1, Nb);
    // --- layer 2: 256 -> 4x64, relu ---
    gemm_mfma<256, 4><<<ggrid, 256, 0, stream>>>(Nb, Wt2, as2, ad2, Hb, ES, ED);
    agg_kernel<4, true><<<agrid, 256, 0, stream>>>(Hb, rowoff, csr, ES, ED, b2, Nb);
    // --- layer 3: 256 -> 1x256, no relu ---
    gemm_mfma<256, 1><<<ggrid, 256, 0, stream>>>(Nb, Wt3, as3, ad3, Hb, ES, ED);
    agg_kernel<1, false><<<agrid, 256, 0, stream>>>(Hb, rowoff, csr, ES, ED, b3, Nb);
    // --- global max pool ---
    pool_k<<<N_GRAPHS_C, 256, 0, stream>>>(Nb, batch, out);
}

// Round 5
// 357.450 us; speedup vs baseline: 4.2715x; 1.3470x over previous
//
#include <hip/hip_runtime.h>
#include <hip/hip_bf16.h>
#include <math.h>

// Problem constants (from reference)
#define N_NODES_C 100000
#define E_ORIG    400000
#define E_TOT     500000   // + self loops
#define N_GRAPHS_C 2000
#define KDIM      256      // HEADS*HID = OUT

typedef __attribute__((ext_vector_type(8))) short short8v;  // 8 bf16 = 4 VGPR
typedef __attribute__((ext_vector_type(4))) float f32x4;

__device__ __forceinline__ void gload_lds16(const void* g, void* l) {
    __builtin_amdgcn_global_load_lds(
        (const __attribute__((address_space(1))) unsigned int*)g,
        (__attribute__((address_space(3))) unsigned int*)l, 16, 0, 0);
}

__device__ __forceinline__ float bflo(unsigned u) { return __uint_as_float(u << 16); }
__device__ __forceinline__ float bfhi(unsigned u) { return __uint_as_float(u & 0xffff0000u); }

// ---------------------------------------------------------------------------
// CSR construction (by destination). Graph is identical for all 3 layers.
// ---------------------------------------------------------------------------
__global__ void count_deg_k(const int* __restrict__ ei, int* __restrict__ deg) {
    int e = blockIdx.x * 256 + threadIdx.x;
    if (e >= E_TOT) return;
    int d = (e < E_ORIG) ? ei[E_ORIG + e] : (e - E_ORIG);
    atomicAdd(&deg[d], 1);
}

__global__ void scan_chunk(const int* __restrict__ in, int* __restrict__ out,
                           int* __restrict__ partials, int n) {
    __shared__ int s[256];
    int tid = threadIdx.x;
    int i = blockIdx.x * 256 + tid;
    int v = (i < n) ? in[i] : 0;
    s[tid] = v;
    __syncthreads();
    for (int off = 1; off < 256; off <<= 1) {
        int t = (tid >= off) ? s[tid - off] : 0;
        __syncthreads();
        s[tid] += t;
        __syncthreads();
    }
    if (i < n) out[i] = s[tid] - v;            // exclusive
    if (tid == 255) partials[blockIdx.x] = s[255];
}

__global__ void scan_partials(int* p, int nb) {
    __shared__ int s[512];
    int tid = threadIdx.x;
    int v = (tid < nb) ? p[tid] : 0;
    s[tid] = v;
    __syncthreads();
    for (int off = 1; off < 512; off <<= 1) {
        int t = (tid >= off) ? s[tid - off] : 0;
        __syncthreads();
        s[tid] += t;
        __syncthreads();
    }
    if (tid < nb) p[tid] = s[tid] - v;         // exclusive
}

__global__ void add_partials(int* out, const int* __restrict__ p, int n) {
    int i = blockIdx.x * 256 + threadIdx.x;
    if (i < n) out[i] += p[blockIdx.x];
}

__global__ void scatter_k(const int* __restrict__ ei, const int* __restrict__ rowoff,
                          int* cursor, int* __restrict__ csr_src,
                          int* __restrict__ csr_dst) {
    int e = blockIdx.x * 256 + threadIdx.x;
    if (e >= E_TOT) return;
    int s, d;
    if (e < E_ORIG) { s = ei[e]; d = ei[E_ORIG + e]; }
    else            { s = e - E_ORIG; d = s; }
    int pos = rowoff[d] + atomicAdd(&cursor[d], 1);
    csr_src[pos] = s;
    csr_dst[pos] = d;
}

// ---------------------------------------------------------------------------
// Input conversions to bf16.
// ---------------------------------------------------------------------------
__global__ void conv_x_k(const float* __restrict__ x, __hip_bfloat16* __restrict__ Xb) {
    int idx = blockIdx.x * 256 + threadIdx.x;          // N*64 total
    if (idx >= N_NODES_C * 64) return;
    int row = idx >> 6, c = idx & 63;
    float v = (c < 58) ? x[row * 58 + c] : 0.f;
    Xb[idx] = __float2bfloat16(v);
}

// Wt[c][kpad] = W[k][c] (zero-padded in k)
template <int K, int KPAD>
__global__ void conv_wt_k(const float* __restrict__ W, __hip_bfloat16* __restrict__ Wt) {
    int idx = blockIdx.x * 256 + threadIdx.x;          // 256*KPAD total
    if (idx >= 256 * KPAD) return;
    int c = idx / KPAD, k = idx - c * KPAD;
    float v = (k < K) ? W[k * 256 + c] : 0.f;
    Wt[idx] = __float2bfloat16(v);
}

// ---------------------------------------------------------------------------
// MFMA bf16 GEMM: H = X @ W  (X:[N][KPAD] bf16, Wt:[256 cols][KPAD] bf16)
// + fused attention dots ES/ED. (unchanged from r4 — verified)
// ---------------------------------------------------------------------------
template <int KPAD, int NH>
__global__ __launch_bounds__(256) void gemm_mfma(
        const __hip_bfloat16* __restrict__ Xb, const __hip_bfloat16* __restrict__ Wt,
        const float* __restrict__ ASRC, const float* __restrict__ ADST,
        __hip_bfloat16* __restrict__ H, float* __restrict__ ES, float* __restrict__ ED) {
    __shared__ char As[64 * 128];                    // [64 rows][64 k] bf16
    __shared__ char Bs[256 * 128];                   // [256 cols][64 k] bf16
    __shared__ float red[2][64][2];                  // NH==1 cross-wave ES/ED

    const int t = threadIdx.x;
    const int wv = t >> 6, lane = t & 63;
    const int wr = wv >> 1, wc = wv & 1;
    const int r15 = lane & 15, hi = lane >> 4;
    const int n0 = blockIdx.x * 64;
    const int srow = lane >> 3;                      // staging: row-within-8
    const int sx = ((lane & 7) ^ srow) * 16;         // pre-swizzled source chunk
    constexpr int KB = KPAD * 2;                     // row bytes

    f32x4 acc[2][8];
#pragma unroll
    for (int m = 0; m < 2; m++)
#pragma unroll
        for (int n = 0; n < 8; n++) acc[m][n] = (f32x4){0.f, 0.f, 0.f, 0.f};

    for (int kt = 0; kt < KPAD / 64; kt++) {
        if (kt) __syncthreads();
        const int k0b = kt * 128;
#pragma unroll
        for (int p = 0; p < 2; p++) {
            int i = wv * 2 + p;
            int gr = n0 + i * 8 + srow;
            if (gr > N_NODES_C - 1) gr = N_NODES_C - 1;
            gload_lds16((const char*)Xb + (size_t)gr * KB + k0b + sx, As + i * 1024);
        }
#pragma unroll
        for (int p = 0; p < 8; p++) {
            int i = wv * 8 + p;
            int col = i * 8 + srow;
            gload_lds16((const char*)Wt + (size_t)col * KB + k0b + sx, Bs + i * 1024);
        }
        asm volatile("s_waitcnt vmcnt(0)" ::: "memory");
        __syncthreads();

#pragma unroll
        for (int ks = 0; ks < 2; ks++) {
            const int cx = ((ks * 4 + hi) ^ (r15 & 7)) * 16;  // swizzled chunk byte
            short8v a0 = *(const short8v*)(As + (wr * 32 + 0  + r15) * 128 + cx);
            short8v a1 = *(const short8v*)(As + (wr * 32 + 16 + r15) * 128 + cx);
            short8v b[8];
#pragma unroll
            for (int n = 0; n < 8; n++)
                b[n] = *(const short8v*)(Bs + (wc * 128 + n * 16 + r15) * 128 + cx);
#pragma unroll
            for (int n = 0; n < 8; n++) {
                acc[0][n] = __builtin_amdgcn_mfma_f32_16x16x32_bf16(a0, b[n], acc[0][n], 0, 0, 0);
                acc[1][n] = __builtin_amdgcn_mfma_f32_16x16x32_bf16(a1, b[n], acc[1][n], 0, 0, 0);
            }
        }
    }

    // ---- epilogue: H (bf16) + attention dots ----
    float asv[8], adv[8];
#pragma unroll
    for (int n = 0; n < 8; n++) {
        int col = wc * 128 + n * 16 + r15;
        asv[n] = ASRC[col];
        adv[n] = ADST[col];
    }

#pragma unroll
    for (int m = 0; m < 2; m++) {
#pragma unroll
        for (int j = 0; j < 4; j++) {
            int lrow = wr * 32 + m * 16 + hi * 4 + j;
            int row = n0 + lrow;
            bool ok = row < N_NODES_C;
            if (ok) {
#pragma unroll
                for (int n = 0; n < 8; n++)
                    H[(size_t)row * KDIM + wc * 128 + n * 16 + r15] =
                        __float2bfloat16(acc[m][n][j]);
            }
            if (NH == 4) {
                float p0s = 0.f, p1s = 0.f, p0d = 0.f, p1d = 0.f;
#pragma unroll
                for (int n = 0; n < 4; n++) {
                    p0s = fmaf(acc[m][n][j], asv[n], p0s);
                    p0d = fmaf(acc[m][n][j], adv[n], p0d);
                    p1s = fmaf(acc[m][n + 4][j], asv[n + 4], p1s);
                    p1d = fmaf(acc[m][n + 4][j], adv[n + 4], p1d);
                }
#pragma unroll
                for (int s = 8; s; s >>= 1) {
                    p0s += __shfl_xor(p0s, s, 16);
                    p0d += __shfl_xor(p0d, s, 16);
                    p1s += __shfl_xor(p1s, s, 16);
                    p1d += __shfl_xor(p1d, s, 16);
                }
                if (r15 == 0 && ok) {
                    ES[row * 4 + wc * 2 + 0] = p0s;
                    ES[row * 4 + wc * 2 + 1] = p1s;
                    ED[row * 4 + wc * 2 + 0] = p0d;
                    ED[row * 4 + wc * 2 + 1] = p1d;
                }
            } else {
                float ps = 0.f, pd = 0.f;
#pragma unroll
                for (int n = 0; n < 8; n++) {
                    ps = fmaf(acc[m][n][j], asv[n], ps);
                    pd = fmaf(acc[m][n][j], adv[n], pd);
                }
#pragma unroll
                for (int s = 8; s; s >>= 1) {
                    ps += __shfl_xor(ps, s, 16);
                    pd += __shfl_xor(pd, s, 16);
                }
                if (r15 == 0) { red[0][lrow][wc] = ps; red[1][lrow][wc] = pd; }
            }
        }
    }
    if (NH == 1) {
        __syncthreads();
        if (t < 64) {
            int row = n0 + t;
            if (row < N_NODES_C) {
                ES[row] = red[0][t][0] + red[0][t][1];
                ED[row] = red[1][t][0] + red[1][t][1];
            }
        }
    }
}

// ---------------------------------------------------------------------------
// Edge-parallel logit precompute: E[slot][h] = leaky_relu(ES[src,h]+ED[dst,h])
// CSR-ordered output -> agg reads it contiguously (no dependent gathers).
// ---------------------------------------------------------------------------
template <int NH>
__global__ __launch_bounds__(256) void edge_e_k(
        const int* __restrict__ csr_src, const int* __restrict__ csr_dst,
        const float* __restrict__ ES, const float* __restrict__ ED,
        float* __restrict__ E) {
    int j = blockIdx.x * 256 + threadIdx.x;
    if (j >= E_TOT) return;
    int s = csr_src[j], d = csr_dst[j];
    if (NH == 4) {
        float4 es = *(const float4*)&ES[s * 4];
        float4 ed = *(const float4*)&ED[d * 4];
        float4 e;
        e.x = es.x + ed.x; e.x = (e.x > 0.f) ? e.x : 0.2f * e.x;
        e.y = es.y + ed.y; e.y = (e.y > 0.f) ? e.y : 0.2f * e.y;
        e.z = es.z + ed.z; e.z = (e.z > 0.f) ? e.z : 0.2f * e.z;
        e.w = es.w + ed.w; e.w = (e.w > 0.f) ? e.w : 0.2f * e.w;
        *(float4*)&E[j * 4] = e;
    } else {
        float e = ES[s] + ED[d];
        E[j] = (e > 0.f) ? e : 0.2f * e;
    }
}

// ---------------------------------------------------------------------------
// Per-dst softmax aggregation: 2 nodes per wave (half-wave of 32 lanes each),
// lane owns 8 channels (16B dwordx4 gathers). Logits come precomputed &
// contiguous from E; manual 2x unroll keeps two H-row gathers in flight.
// ---------------------------------------------------------------------------
template <int NH, bool RELU>
__global__ __launch_bounds__(256) void agg_kernel(
        const __hip_bfloat16* __restrict__ H, const int* __restrict__ rowoff,
        const int* __restrict__ csr_src, const float* __restrict__ E,
        const float* __restrict__ bias, __hip_bfloat16* __restrict__ Out) {
    int node = blockIdx.x * 8 + (threadIdx.x >> 5);   // grid*8 == N exactly
    int l = threadIdx.x & 31;
    int c0 = l * 8;
    int head = (NH == 4) ? (l >> 3) : 0;
    int beg = rowoff[node], end = rowoff[node + 1];

    float m = -1e30f;
    for (int j = beg; j < end; j++) m = fmaxf(m, E[j * NH + head]);

    float s = 0.f;
    float a[8];
#pragma unroll
    for (int i = 0; i < 8; i++) a[i] = 0.f;
    const unsigned short* Hu = (const unsigned short*)H;

#define ACC8(v, p) \
    a[0] = fmaf(p, bflo(v.x), a[0]); a[1] = fmaf(p, bfhi(v.x), a[1]); \
    a[2] = fmaf(p, bflo(v.y), a[2]); a[3] = fmaf(p, bfhi(v.y), a[3]); \
    a[4] = fmaf(p, bflo(v.z), a[4]); a[5] = fmaf(p, bfhi(v.z), a[5]); \
    a[6] = fmaf(p, bflo(v.w), a[6]); a[7] = fmaf(p, bfhi(v.w), a[7]);

    int j = beg;
    for (; j + 2 <= end; j += 2) {
        int s0 = csr_src[j], s1 = csr_src[j + 1];
        float e0 = E[j * NH + head], e1 = E[(j + 1) * NH + head];
        uint4 v0 = *(const uint4*)(Hu + (size_t)s0 * KDIM + c0);
        uint4 v1 = *(const uint4*)(Hu + (size_t)s1 * KDIM + c0);
        float p0 = __expf(e0 - m), p1 = __expf(e1 - m);
        s += p0 + p1;
        ACC8(v0, p0)
        ACC8(v1, p1)
    }
    if (j < end) {
        int s0 = csr_src[j];
        float e0 = E[j * NH + head];
        uint4 v0 = *(const uint4*)(Hu + (size_t)s0 * KDIM + c0);
        float p0 = __expf(e0 - m);
        s += p0;
        ACC8(v0, p0)
    }
#undef ACC8

    float inv = 1.f / s;
    float4 b0 = *(const float4*)&bias[c0];
    float4 b1 = *(const float4*)&bias[c0 + 4];
    float o[8];
    o[0] = fmaf(a[0], inv, b0.x); o[1] = fmaf(a[1], inv, b0.y);
    o[2] = fmaf(a[2], inv, b0.z); o[3] = fmaf(a[3], inv, b0.w);
    o[4] = fmaf(a[4], inv, b1.x); o[5] = fmaf(a[5], inv, b1.y);
    o[6] = fmaf(a[6], inv, b1.z); o[7] = fmaf(a[7], inv, b1.w);
    __hip_bfloat16 rb[8];
#pragma unroll
    for (int i = 0; i < 8; i++) {
        float v = RELU ? fmaxf(o[i], 0.f) : o[i];
        rb[i] = __float2bfloat16(v);
    }
    *(uint4*)&Out[(size_t)node * KDIM + c0] = *(uint4*)rb;
}

// ---------------------------------------------------------------------------
// Global max pool over graphs (bf16 input, f32 output).
// ---------------------------------------------------------------------------
__global__ __launch_bounds__(256) void pool_k(
        const __hip_bfloat16* __restrict__ O, const int* __restrict__ batch,
        float* __restrict__ out) {
    __shared__ int range[2];
    int g = blockIdx.x, k = threadIdx.x;
    if (k < 2) {
        int v = g + k;
        int lo = 0, hi = N_NODES_C;
        while (lo < hi) { int mid = (lo + hi) >> 1; if (batch[mid] < v) lo = mid + 1; else hi = mid; }
        range[k] = lo;
    }
    __syncthreads();
    float m = -INFINITY;
    for (int i = range[0]; i < range[1]; i++)
        m = fmaxf(m, __bfloat162float(O[(size_t)i * KDIM + k]));
    out[(size_t)g * KDIM + k] = m;
}

// ---------------------------------------------------------------------------
extern "C" void kernel_launch(void* const* d_in, const int* in_sizes, int n_in,
                              void* d_out, int out_size, void* d_ws, size_t ws_size,
                              hipStream_t stream) {
    const float* x     = (const float*)d_in[0];
    const int*   ei    = (const int*)d_in[1];
    const int*   batch = (const int*)d_in[2];
    const float* W1  = (const float*)d_in[3];
    const float* as1 = (const float*)d_in[4];
    const float* ad1 = (const float*)d_in[5];
    const float* b1  = (const float*)d_in[6];
    const float* W2  = (const float*)d_in[7];
    const float* as2 = (const float*)d_in[8];
    const float* ad2 = (const float*)d_in[9];
    const float* b2  = (const float*)d_in[10];
    const float* W3  = (const float*)d_in[11];
    const float* as3 = (const float*)d_in[12];
    const float* ad3 = (const float*)d_in[13];
    const float* b3  = (const float*)d_in[14];
    float* out = (float*)d_out;

    // Workspace layout (~135 MB)
    char* p = (char*)d_ws;
    auto alloc = [&](size_t bytes) { char* r = p; p += (bytes + 255) & ~(size_t)255; return r; };
    __hip_bfloat16* Xb  = (__hip_bfloat16*)alloc((size_t)N_NODES_C * 64 * 2);
    __hip_bfloat16* Hb  = (__hip_bfloat16*)alloc((size_t)N_NODES_C * KDIM * 2);
    __hip_bfloat16* Nb  = (__hip_bfloat16*)alloc((size_t)N_NODES_C * KDIM * 2);
    __hip_bfloat16* Wt1 = (__hip_bfloat16*)alloc(256 * 64 * 2);
    __hip_bfloat16* Wt2 = (__hip_bfloat16*)alloc(256 * 256 * 2);
    __hip_bfloat16* Wt3 = (__hip_bfloat16*)alloc(256 * 256 * 2);
    float* ES     = (float*)alloc((size_t)N_NODES_C * 4 * 4);
    float* ED     = (float*)alloc((size_t)N_NODES_C * 4 * 4);
    float* Ecoef  = (float*)alloc((size_t)E_TOT * 4 * 4);
    int* deg      = (int*)alloc((N_NODES_C + 1) * 4);
    int* rowoff   = (int*)alloc((N_NODES_C + 1) * 4);
    int* cursor   = (int*)alloc(N_NODES_C * 4);
    int* csr      = (int*)alloc((size_t)E_TOT * 4);
    int* csrd     = (int*)alloc((size_t)E_TOT * 4);
    int* partials = (int*)alloc(512 * 4);

    // --- input conversions ---
    conv_x_k<<<(N_NODES_C * 64 + 255) / 256, 256, 0, stream>>>(x, Xb);
    conv_wt_k<58, 64><<<64, 256, 0, stream>>>(W1, Wt1);
    conv_wt_k<256, 256><<<256, 256, 0, stream>>>(W2, Wt2);
    conv_wt_k<256, 256><<<256, 256, 0, stream>>>(W3, Wt3);

    // --- build CSR ---
    hipMemsetAsync(deg, 0, (N_NODES_C + 1) * 4, stream);
    hipMemsetAsync(cursor, 0, N_NODES_C * 4, stream);
    int egrid = (E_TOT + 255) / 256;
    count_deg_k<<<egrid, 256, 0, stream>>>(ei, deg);
    int nb = (N_NODES_C + 1 + 255) / 256;           // 391
    scan_chunk<<<nb, 256, 0, stream>>>(deg, rowoff, partials, N_NODES_C + 1);
    scan_partials<<<1, 512, 0, stream>>>(partials, nb);
    add_partials<<<nb, 256, 0, stream>>>(rowoff, partials, N_NODES_C + 1);
    scatter_k<<<egrid, 256, 0, stream>>>(ei, rowoff, cursor, csr, csrd);

    int ggrid = (N_NODES_C + 63) / 64;               // 1563
    int agrid = N_NODES_C / 8;                       // 12500 (exact)
    // --- layer 1: 58(->64) -> 4x64, relu ---
    gemm_mfma<64, 4><<<ggrid, 256, 0, stream>>>(Xb, Wt1, as1, ad1, Hb, ES, ED);
    edge_e_k<4><<<egrid, 256, 0, stream>>>(csr, csrd, ES, ED, Ecoef);
    agg_kernel<4, true><<<agrid, 256, 0, stream>>>(Hb, rowoff, csr, Ecoef, b1, Nb);
    // --- layer 2: 256 -> 4x64, relu ---
    gemm_mfma<256, 4><<<ggrid, 256, 0, stream>>>(Nb, Wt2, as2, ad2, Hb, ES, ED);
    edge_e_k<4><<<egrid, 256, 0, stream>>>(csr, csrd, ES, ED, Ecoef);
    agg_kernel<4, true><<<agrid, 256, 0, stream>>>(Hb, rowoff, csr, Ecoef, b2, Nb);
    // --- layer 3: 256 -> 1x256, no relu ---
    gemm_mfma<256, 1><<<ggrid, 256, 0, stream>>>(Nb, Wt3, as3, ad3, Hb, ES, ED);
    edge_e_k<1><<<egrid, 256, 0, stream>>>(csr, csrd, ES, ED, Ecoef);
    agg_kernel<1, false><<<agrid, 256, 0, stream>>>(Hb, rowoff, csr, Ecoef, b3, Nb);
    // --- global max pool ---
    pool_k<<<N_GRAPHS_C, 256, 0, stream>>>(Nb, batch, out);
}

// Round 6
// 353.023 us; speedup vs baseline: 4.3251x; 1.0125x over previous
//
#include <hip/hip_runtime.h>
#include <hip/hip_bf16.h>
#include <math.h>

// Problem constants (from reference)
#define N_NODES_C 100000
#define E_ORIG    400000
#define E_TOT     500000   // + self loops
#define N_GRAPHS_C 2000
#define KDIM      256      // HEADS*HID = OUT

typedef __attribute__((ext_vector_type(8))) short short8v;  // 8 bf16 = 4 VGPR
typedef __attribute__((ext_vector_type(4))) float f32x4;

__device__ __forceinline__ void gload_lds16(const void* g, void* l) {
    __builtin_amdgcn_global_load_lds(
        (const __attribute__((address_space(1))) unsigned int*)g,
        (__attribute__((address_space(3))) unsigned int*)l, 16, 0, 0);
}

__device__ __forceinline__ float bflo(unsigned u) { return __uint_as_float(u << 16); }
__device__ __forceinline__ float bfhi(unsigned u) { return __uint_as_float(u & 0xffff0000u); }

// ---------------------------------------------------------------------------
// CSR construction (by destination). Graph is identical for all 3 layers.
// ---------------------------------------------------------------------------
__global__ void count_deg_k(const int* __restrict__ ei, int* __restrict__ deg) {
    int e = blockIdx.x * 256 + threadIdx.x;
    if (e >= E_TOT) return;
    int d = (e < E_ORIG) ? ei[E_ORIG + e] : (e - E_ORIG);
    atomicAdd(&deg[d], 1);
}

__global__ void scan_chunk(const int* __restrict__ in, int* __restrict__ out,
                           int* __restrict__ partials, int n) {
    __shared__ int s[256];
    int tid = threadIdx.x;
    int i = blockIdx.x * 256 + tid;
    int v = (i < n) ? in[i] : 0;
    s[tid] = v;
    __syncthreads();
    for (int off = 1; off < 256; off <<= 1) {
        int t = (tid >= off) ? s[tid - off] : 0;
        __syncthreads();
        s[tid] += t;
        __syncthreads();
    }
    if (i < n) out[i] = s[tid] - v;            // exclusive
    if (tid == 255) partials[blockIdx.x] = s[255];
}

__global__ void scan_partials(int* p, int nb) {
    __shared__ int s[512];
    int tid = threadIdx.x;
    int v = (tid < nb) ? p[tid] : 0;
    s[tid] = v;
    __syncthreads();
    for (int off = 1; off < 512; off <<= 1) {
        int t = (tid >= off) ? s[tid - off] : 0;
        __syncthreads();
        s[tid] += t;
        __syncthreads();
    }
    if (tid < nb) p[tid] = s[tid] - v;         // exclusive
}

__global__ void add_partials(int* out, const int* __restrict__ p, int n) {
    int i = blockIdx.x * 256 + threadIdx.x;
    if (i < n) out[i] += p[blockIdx.x];
}

__global__ void scatter_k(const int* __restrict__ ei, const int* __restrict__ rowoff,
                          int* cursor, int* __restrict__ csr_src) {
    int e = blockIdx.x * 256 + threadIdx.x;
    if (e >= E_TOT) return;
    int s, d;
    if (e < E_ORIG) { s = ei[e]; d = ei[E_ORIG + e]; }
    else            { s = e - E_ORIG; d = s; }
    int pos = rowoff[d] + atomicAdd(&cursor[d], 1);
    csr_src[pos] = s;
}

// ---------------------------------------------------------------------------
// Input conversions to bf16.
// ---------------------------------------------------------------------------
__global__ void conv_x_k(const float* __restrict__ x, __hip_bfloat16* __restrict__ Xb) {
    int idx = blockIdx.x * 256 + threadIdx.x;          // N*64 total
    if (idx >= N_NODES_C * 64) return;
    int row = idx >> 6, c = idx & 63;
    float v = (c < 58) ? x[row * 58 + c] : 0.f;
    Xb[idx] = __float2bfloat16(v);
}

// Wt[c][kpad] = W[k][c] (zero-padded in k)
template <int K, int KPAD>
__global__ void conv_wt_k(const float* __restrict__ W, __hip_bfloat16* __restrict__ Wt) {
    int idx = blockIdx.x * 256 + threadIdx.x;          // 256*KPAD total
    if (idx >= 256 * KPAD) return;
    int c = idx / KPAD, k = idx - c * KPAD;
    float v = (k < K) ? W[k * 256 + c] : 0.f;
    Wt[idx] = __float2bfloat16(v);
}

// ---------------------------------------------------------------------------
// MFMA bf16 GEMM: H = X @ W  (X:[N][KPAD] bf16, Wt:[256 cols][KPAD] bf16)
// + fused attention dots ES/ED. (unchanged — verified r4/r5)
// ---------------------------------------------------------------------------
template <int KPAD, int NH>
__global__ __launch_bounds__(256) void gemm_mfma(
        const __hip_bfloat16* __restrict__ Xb, const __hip_bfloat16* __restrict__ Wt,
        const float* __restrict__ ASRC, const float* __restrict__ ADST,
        __hip_bfloat16* __restrict__ H, float* __restrict__ ES, float* __restrict__ ED) {
    __shared__ char As[64 * 128];                    // [64 rows][64 k] bf16
    __shared__ char Bs[256 * 128];                   // [256 cols][64 k] bf16
    __shared__ float red[2][64][2];                  // NH==1 cross-wave ES/ED

    const int t = threadIdx.x;
    const int wv = t >> 6, lane = t & 63;
    const int wr = wv >> 1, wc = wv & 1;
    const int r15 = lane & 15, hi = lane >> 4;
    const int n0 = blockIdx.x * 64;
    const int srow = lane >> 3;                      // staging: row-within-8
    const int sx = ((lane & 7) ^ srow) * 16;         // pre-swizzled source chunk
    constexpr int KB = KPAD * 2;                     // row bytes

    f32x4 acc[2][8];
#pragma unroll
    for (int m = 0; m < 2; m++)
#pragma unroll
        for (int n = 0; n < 8; n++) acc[m][n] = (f32x4){0.f, 0.f, 0.f, 0.f};

    for (int kt = 0; kt < KPAD / 64; kt++) {
        if (kt) __syncthreads();
        const int k0b = kt * 128;
#pragma unroll
        for (int p = 0; p < 2; p++) {
            int i = wv * 2 + p;
            int gr = n0 + i * 8 + srow;
            if (gr > N_NODES_C - 1) gr = N_NODES_C - 1;
            gload_lds16((const char*)Xb + (size_t)gr * KB + k0b + sx, As + i * 1024);
        }
#pragma unroll
        for (int p = 0; p < 8; p++) {
            int i = wv * 8 + p;
            int col = i * 8 + srow;
            gload_lds16((const char*)Wt + (size_t)col * KB + k0b + sx, Bs + i * 1024);
        }
        asm volatile("s_waitcnt vmcnt(0)" ::: "memory");
        __syncthreads();

#pragma unroll
        for (int ks = 0; ks < 2; ks++) {
            const int cx = ((ks * 4 + hi) ^ (r15 & 7)) * 16;  // swizzled chunk byte
            short8v a0 = *(const short8v*)(As + (wr * 32 + 0  + r15) * 128 + cx);
            short8v a1 = *(const short8v*)(As + (wr * 32 + 16 + r15) * 128 + cx);
            short8v b[8];
#pragma unroll
            for (int n = 0; n < 8; n++)
                b[n] = *(const short8v*)(Bs + (wc * 128 + n * 16 + r15) * 128 + cx);
#pragma unroll
            for (int n = 0; n < 8; n++) {
                acc[0][n] = __builtin_amdgcn_mfma_f32_16x16x32_bf16(a0, b[n], acc[0][n], 0, 0, 0);
                acc[1][n] = __builtin_amdgcn_mfma_f32_16x16x32_bf16(a1, b[n], acc[1][n], 0, 0, 0);
            }
        }
    }

    // ---- epilogue: H (bf16) + attention dots ----
    float asv[8], adv[8];
#pragma unroll
    for (int n = 0; n < 8; n++) {
        int col = wc * 128 + n * 16 + r15;
        asv[n] = ASRC[col];
        adv[n] = ADST[col];
    }

#pragma unroll
    for (int m = 0; m < 2; m++) {
#pragma unroll
        for (int j = 0; j < 4; j++) {
            int lrow = wr * 32 + m * 16 + hi * 4 + j;
            int row = n0 + lrow;
            bool ok = row < N_NODES_C;
            if (ok) {
#pragma unroll
                for (int n = 0; n < 8; n++)
                    H[(size_t)row * KDIM + wc * 128 + n * 16 + r15] =
                        __float2bfloat16(acc[m][n][j]);
            }
            if (NH == 4) {
                float p0s = 0.f, p1s = 0.f, p0d = 0.f, p1d = 0.f;
#pragma unroll
                for (int n = 0; n < 4; n++) {
                    p0s = fmaf(acc[m][n][j], asv[n], p0s);
                    p0d = fmaf(acc[m][n][j], adv[n], p0d);
                    p1s = fmaf(acc[m][n + 4][j], asv[n + 4], p1s);
                    p1d = fmaf(acc[m][n + 4][j], adv[n + 4], p1d);
                }
#pragma unroll
                for (int s = 8; s; s >>= 1) {
                    p0s += __shfl_xor(p0s, s, 16);
                    p0d += __shfl_xor(p0d, s, 16);
                    p1s += __shfl_xor(p1s, s, 16);
                    p1d += __shfl_xor(p1d, s, 16);
                }
                if (r15 == 0 && ok) {
                    ES[row * 4 + wc * 2 + 0] = p0s;
                    ES[row * 4 + wc * 2 + 1] = p1s;
                    ED[row * 4 + wc * 2 + 0] = p0d;
                    ED[row * 4 + wc * 2 + 1] = p1d;
                }
            } else {
                float ps = 0.f, pd = 0.f;
#pragma unroll
                for (int n = 0; n < 8; n++) {
                    ps = fmaf(acc[m][n][j], asv[n], ps);
                    pd = fmaf(acc[m][n][j], adv[n], pd);
                }
#pragma unroll
                for (int s = 8; s; s >>= 1) {
                    ps += __shfl_xor(ps, s, 16);
                    pd += __shfl_xor(pd, s, 16);
                }
                if (r15 == 0) { red[0][lrow][wc] = ps; red[1][lrow][wc] = pd; }
            }
        }
    }
    if (NH == 1) {
        __syncthreads();
        if (t < 64) {
            int row = n0 + t;
            if (row < N_NODES_C) {
                ES[row] = red[0][t][0] + red[0][t][1];
                ED[row] = red[1][t][0] + red[1][t][1];
            }
        }
    }
}

// ---------------------------------------------------------------------------
// Fused per-dst softmax aggregation. 2 nodes per wave (32 lanes each; lane
// owns 8 channels = 16B gathers). Register-staged: all csr_src slots loaded
// into registers (static full unroll, predicated), then all ES gathers issued
// independently, then up to MAXD independent H-row gathers — max MLP.
// Degrees > MAXD (~2 nodes / 100k at Poisson(4)+1) take a rare slow path.
// ---------------------------------------------------------------------------
#define MAXD 16
template <int NH, bool RELU>
__global__ __launch_bounds__(256) void agg_kernel(
        const __hip_bfloat16* __restrict__ H, const int* __restrict__ rowoff,
        const int* __restrict__ csr_src, const float* __restrict__ ES,
        const float* __restrict__ ED, const float* __restrict__ bias,
        __hip_bfloat16* __restrict__ Out) {
    int node = blockIdx.x * 8 + (threadIdx.x >> 5);   // grid*8 == N exactly
    int l = threadIdx.x & 31;
    int c0 = l * 8;
    int head = (NH == 4) ? (l >> 3) : 0;
    int beg = rowoff[node], end = rowoff[node + 1];
    int deg = end - beg;
    float edv = ED[node * NH + head];

    // ---- pass 1: srcs -> regs, independent ES gathers, logits in regs ----
    int srcs[MAXD];
    float ev[MAXD];
#pragma unroll
    for (int i = 0; i < MAXD; i++) {
        srcs[i] = 0;
        if (i < deg) srcs[i] = csr_src[beg + i];
    }
#pragma unroll
    for (int i = 0; i < MAXD; i++) {
        ev[i] = -1e30f;
        if (i < deg) {
            float e = ES[srcs[i] * NH + head] + edv;
            ev[i] = (e > 0.f) ? e : 0.2f * e;
        }
    }
    float m = -1e30f;
#pragma unroll
    for (int i = 0; i < MAXD; i++) m = fmaxf(m, ev[i]);
    if (deg > MAXD) {                                  // rare
        for (int j = beg + MAXD; j < end; j++) {
            float e = ES[csr_src[j] * NH + head] + edv;
            e = (e > 0.f) ? e : 0.2f * e;
            m = fmaxf(m, e);
        }
    }

    // ---- pass 2: weights in regs, independent H-row gathers ----
    float s = 0.f;
#pragma unroll
    for (int i = 0; i < MAXD; i++) {
        ev[i] = __expf(ev[i] - m);                     // invalid -> exp(-inf)=0
        s += ev[i];
    }
    float a[8];
#pragma unroll
    for (int i = 0; i < 8; i++) a[i] = 0.f;
    const unsigned short* Hu = (const unsigned short*)H;

#define ACC8(v, p) \
    a[0] = fmaf(p, bflo(v.x), a[0]); a[1] = fmaf(p, bfhi(v.x), a[1]); \
    a[2] = fmaf(p, bflo(v.y), a[2]); a[3] = fmaf(p, bfhi(v.y), a[3]); \
    a[4] = fmaf(p, bflo(v.z), a[4]); a[5] = fmaf(p, bfhi(v.z), a[5]); \
    a[6] = fmaf(p, bflo(v.w), a[6]); a[7] = fmaf(p, bfhi(v.w), a[7]);

#pragma unroll
    for (int i = 0; i < MAXD; i++) {
        if (i < deg) {
            uint4 v = *(const uint4*)(Hu + (size_t)srcs[i] * KDIM + c0);
            float p = ev[i];
            ACC8(v, p)
        }
    }
    if (deg > MAXD) {                                  // rare
        for (int j = beg + MAXD; j < end; j++) {
            int sj = csr_src[j];
            float e = ES[sj * NH + head] + edv;
            e = (e > 0.f) ? e : 0.2f * e;
            float p = __expf(e - m);
            s += p;
            uint4 v = *(const uint4*)(Hu + (size_t)sj * KDIM + c0);
            ACC8(v, p)
        }
    }
#undef ACC8

    float inv = 1.f / s;
    float4 b0 = *(const float4*)&bias[c0];
    float4 b1 = *(const float4*)&bias[c0 + 4];
    float o[8];
    o[0] = fmaf(a[0], inv, b0.x); o[1] = fmaf(a[1], inv, b0.y);
    o[2] = fmaf(a[2], inv, b0.z); o[3] = fmaf(a[3], inv, b0.w);
    o[4] = fmaf(a[4], inv, b1.x); o[5] = fmaf(a[5], inv, b1.y);
    o[6] = fmaf(a[6], inv, b1.z); o[7] = fmaf(a[7], inv, b1.w);
    __hip_bfloat16 rb[8];
#pragma unroll
    for (int i = 0; i < 8; i++) {
        float v = RELU ? fmaxf(o[i], 0.f) : o[i];
        rb[i] = __float2bfloat16(v);
    }
    *(uint4*)&Out[(size_t)node * KDIM + c0] = *(uint4*)rb;
}

// ---------------------------------------------------------------------------
// Global max pool over graphs. 4 rows in flight (wave = row offset), uint2
// loads (4 bf16 channels/thread), LDS cross-wave combine.
// ---------------------------------------------------------------------------
__global__ __launch_bounds__(256) void pool_k(
        const __hip_bfloat16* __restrict__ O, const int* __restrict__ batch,
        float* __restrict__ out) {
    __shared__ int range[2];
    __shared__ float red[3][256];
    int g = blockIdx.x, k = threadIdx.x;
    if (k < 2) {
        int v = g + k;
        int lo = 0, hi = N_NODES_C;
        while (lo < hi) { int mid = (lo + hi) >> 1; if (batch[mid] < v) lo = mid + 1; else hi = mid; }
        range[k] = lo;
    }
    __syncthreads();
    int cg = k & 63;                 // channels cg*4 .. cg*4+3
    int ro = k >> 6;                 // wave = row offset
    float m0 = -INFINITY, m1 = -INFINITY, m2 = -INFINITY, m3 = -INFINITY;
    const unsigned short* Ou = (const unsigned short*)O;
    for (int i = range[0] + ro; i < range[1]; i += 4) {
        uint2 v = *(const uint2*)(Ou + (size_t)i * KDIM + cg * 4);
        m0 = fmaxf(m0, bflo(v.x)); m1 = fmaxf(m1, bfhi(v.x));
        m2 = fmaxf(m2, bflo(v.y)); m3 = fmaxf(m3, bfhi(v.y));
    }
    if (ro) {
        red[ro - 1][cg * 4 + 0] = m0; red[ro - 1][cg * 4 + 1] = m1;
        red[ro - 1][cg * 4 + 2] = m2; red[ro - 1][cg * 4 + 3] = m3;
    }
    __syncthreads();
    if (ro == 0) {
        m0 = fmaxf(fmaxf(m0, red[0][cg * 4 + 0]), fmaxf(red[1][cg * 4 + 0], red[2][cg * 4 + 0]));
        m1 = fmaxf(fmaxf(m1, red[0][cg * 4 + 1]), fmaxf(red[1][cg * 4 + 1], red[2][cg * 4 + 1]));
        m2 = fmaxf(fmaxf(m2, red[0][cg * 4 + 2]), fmaxf(red[1][cg * 4 + 2], red[2][cg * 4 + 2]));
        m3 = fmaxf(fmaxf(m3, red[0][cg * 4 + 3]), fmaxf(red[1][cg * 4 + 3], red[2][cg * 4 + 3]));
        float4 o = make_float4(m0, m1, m2, m3);
        *(float4*)&out[(size_t)g * KDIM + cg * 4] = o;
    }
}

// ---------------------------------------------------------------------------
extern "C" void kernel_launch(void* const* d_in, const int* in_sizes, int n_in,
                              void* d_out, int out_size, void* d_ws, size_t ws_size,
                              hipStream_t stream) {
    const float* x     = (const float*)d_in[0];
    const int*   ei    = (const int*)d_in[1];
    const int*   batch = (const int*)d_in[2];
    const float* W1  = (const float*)d_in[3];
    const float* as1 = (const float*)d_in[4];
    const float* ad1 = (const float*)d_in[5];
    const float* b1  = (const float*)d_in[6];
    const float* W2  = (const float*)d_in[7];
    const float* as2 = (const float*)d_in[8];
    const float* ad2 = (const float*)d_in[9];
    const float* b2  = (const float*)d_in[10];
    const float* W3  = (const float*)d_in[11];
    const float* as3 = (const float*)d_in[12];
    const float* ad3 = (const float*)d_in[13];
    const float* b3  = (const float*)d_in[14];
    float* out = (float*)d_out;

    // Workspace layout (~120 MB)
    char* p = (char*)d_ws;
    auto alloc = [&](size_t bytes) { char* r = p; p += (bytes + 255) & ~(size_t)255; return r; };
    __hip_bfloat16* Xb  = (__hip_bfloat16*)alloc((size_t)N_NODES_C * 64 * 2);
    __hip_bfloat16* Hb  = (__hip_bfloat16*)alloc((size_t)N_NODES_C * KDIM * 2);
    __hip_bfloat16* Nb  = (__hip_bfloat16*)alloc((size_t)N_NODES_C * KDIM * 2);
    __hip_bfloat16* Wt1 = (__hip_bfloat16*)alloc(256 * 64 * 2);
    __hip_bfloat16* Wt2 = (__hip_bfloat16*)alloc(256 * 256 * 2);
    __hip_bfloat16* Wt3 = (__hip_bfloat16*)alloc(256 * 256 * 2);
    float* ES     = (float*)alloc((size_t)N_NODES_C * 4 * 4);
    float* ED     = (float*)alloc((size_t)N_NODES_C * 4 * 4);
    int* deg      = (int*)alloc((N_NODES_C + 1) * 4);
    int* rowoff   = (int*)alloc((N_NODES_C + 1) * 4);
    int* cursor   = (int*)alloc(N_NODES_C * 4);
    int* csr      = (int*)alloc((size_t)E_TOT * 4 + 256);   // +pad
    int* partials = (int*)alloc(512 * 4);

    // --- input conversions ---
    conv_x_k<<<(N_NODES_C * 64 + 255) / 256, 256, 0, stream>>>(x, Xb);
    conv_wt_k<58, 64><<<64, 256, 0, stream>>>(W1, Wt1);
    conv_wt_k<256, 256><<<256, 256, 0, stream>>>(W2, Wt2);
    conv_wt_k<256, 256><<<256, 256, 0, stream>>>(W3, Wt3);

    // --- build CSR ---
    hipMemsetAsync(deg, 0, (N_NODES_C + 1) * 4, stream);
    hipMemsetAsync(cursor, 0, N_NODES_C * 4, stream);
    int egrid = (E_TOT + 255) / 256;
    count_deg_k<<<egrid, 256, 0, stream>>>(ei, deg);
    int nb = (N_NODES_C + 1 + 255) / 256;           // 391
    scan_chunk<<<nb, 256, 0, stream>>>(deg, rowoff, partials, N_NODES_C + 1);
    scan_partials<<<1, 512, 0, stream>>>(partials, nb);
    add_partials<<<nb, 256, 0, stream>>>(rowoff, partials, N_NODES_C + 1);
    scatter_k<<<egrid, 256, 0, stream>>>(ei, rowoff, cursor, csr);

    int ggrid = (N_NODES_C + 63) / 64;               // 1563
    int agrid = N_NODES_C / 8;                       // 12500 (exact)
    // --- layer 1: 58(->64) -> 4x64, relu ---
    gemm_mfma<64, 4><<<ggrid, 256, 0, stream>>>(Xb, Wt1, as1, ad1, Hb, ES, ED);
    agg_kernel<4, true><<<agrid, 256, 0, stream>>>(Hb, rowoff, csr, ES, ED, b1, Nb);
    // --- layer 2: 256 -> 4x64, relu ---
    gemm_mfma<256, 4><<<ggrid, 256, 0, stream>>>(Nb, Wt2, as2, ad2, Hb, ES, ED);
    agg_kernel<4, true><<<agrid, 256, 0, stream>>>(Hb, rowoff, csr, ES, ED, b2, Nb);
    // --- layer 3: 256 -> 1x256, no relu ---
    gemm_mfma<256, 1><<<ggrid, 256, 0, stream>>>(Nb, Wt3, as3, ad3, Hb, ES, ED);
    agg_kernel<1, false><<<agrid, 256, 0, stream>>>(Hb, rowoff, csr, ES, ED, b3, Nb);
    // --- global max pool ---
    pool_k<<<N_GRAPHS_C, 256, 0, stream>>>(Nb, batch, out);
}

// Round 7
// 341.708 us; speedup vs baseline: 4.4683x; 1.0331x over previous
//
#include <hip/hip_runtime.h>
#include <hip/hip_bf16.h>
#include <math.h>

// Problem constants (from reference)
#define N_NODES_C 100000
#define E_ORIG    400000
#define E_TOT     500000   // + self loops
#define N_GRAPHS_C 2000
#define KDIM      256      // HEADS*HID = OUT

typedef __attribute__((ext_vector_type(8))) short short8v;  // 8 bf16 = 4 VGPR
typedef __attribute__((ext_vector_type(4))) float f32x4;

__device__ __forceinline__ void gload_lds16(const void* g, void* l) {
    __builtin_amdgcn_global_load_lds(
        (const __attribute__((address_space(1))) unsigned int*)g,
        (__attribute__((address_space(3))) unsigned int*)l, 16, 0, 0);
}

__device__ __forceinline__ float bflo(unsigned u) { return __uint_as_float(u << 16); }
__device__ __forceinline__ float bfhi(unsigned u) { return __uint_as_float(u & 0xffff0000u); }

// ---------------------------------------------------------------------------
// CSR construction (by destination). Graph is identical for all 3 layers.
// ---------------------------------------------------------------------------
__global__ void count_deg_k(const int* __restrict__ ei, int* __restrict__ deg) {
    int e = blockIdx.x * 256 + threadIdx.x;
    if (e >= E_TOT) return;
    int d = (e < E_ORIG) ? ei[E_ORIG + e] : (e - E_ORIG);
    atomicAdd(&deg[d], 1);
}

__global__ void scan_chunk(const int* __restrict__ in, int* __restrict__ out,
                           int* __restrict__ partials, int n) {
    __shared__ int s[256];
    int tid = threadIdx.x;
    int i = blockIdx.x * 256 + tid;
    int v = (i < n) ? in[i] : 0;
    s[tid] = v;
    __syncthreads();
    for (int off = 1; off < 256; off <<= 1) {
        int t = (tid >= off) ? s[tid - off] : 0;
        __syncthreads();
        s[tid] += t;
        __syncthreads();
    }
    if (i < n) out[i] = s[tid] - v;            // exclusive
    if (tid == 255) partials[blockIdx.x] = s[255];
}

__global__ void scan_partials(int* p, int nb) {
    __shared__ int s[512];
    int tid = threadIdx.x;
    int v = (tid < nb) ? p[tid] : 0;
    s[tid] = v;
    __syncthreads();
    for (int off = 1; off < 512; off <<= 1) {
        int t = (tid >= off) ? s[tid - off] : 0;
        __syncthreads();
        s[tid] += t;
        __syncthreads();
    }
    if (tid < nb) p[tid] = s[tid] - v;         // exclusive
}

__global__ void add_partials(int* out, const int* __restrict__ p, int n) {
    int i = blockIdx.x * 256 + threadIdx.x;
    if (i < n) out[i] += p[blockIdx.x];
}

__global__ void scatter_k(const int* __restrict__ ei, const int* __restrict__ rowoff,
                          int* cursor, int* __restrict__ csr_src,
                          int* __restrict__ csr_dst) {
    int e = blockIdx.x * 256 + threadIdx.x;
    if (e >= E_TOT) return;
    int s, d;
    if (e < E_ORIG) { s = ei[e]; d = ei[E_ORIG + e]; }
    else            { s = e - E_ORIG; d = s; }
    int pos = rowoff[d] + atomicAdd(&cursor[d], 1);
    csr_src[pos] = s;
    csr_dst[pos] = d;
}

// ---------------------------------------------------------------------------
// Input conversions to bf16.
// ---------------------------------------------------------------------------
__global__ void conv_x_k(const float* __restrict__ x, __hip_bfloat16* __restrict__ Xb) {
    int idx = blockIdx.x * 256 + threadIdx.x;          // N*64 total
    if (idx >= N_NODES_C * 64) return;
    int row = idx >> 6, c = idx & 63;
    float v = (c < 58) ? x[row * 58 + c] : 0.f;
    Xb[idx] = __float2bfloat16(v);
}

// Wt[c][kpad] = W[k][c] (zero-padded in k)
template <int K, int KPAD>
__global__ void conv_wt_k(const float* __restrict__ W, __hip_bfloat16* __restrict__ Wt) {
    int idx = blockIdx.x * 256 + threadIdx.x;          // 256*KPAD total
    if (idx >= 256 * KPAD) return;
    int c = idx / KPAD, k = idx - c * KPAD;
    float v = (k < K) ? W[k * 256 + c] : 0.f;
    Wt[idx] = __float2bfloat16(v);
}

// ---------------------------------------------------------------------------
// MFMA bf16 GEMM: H = X @ W  (X:[N][KPAD] bf16, Wt:[256 cols][KPAD] bf16)
// + fused attention dots ES/ED.
// Block: 128 rows x 256 cols, 4 waves. Wave tile 64x128 (wr=wv>>1, wc=wv&1),
// acc[4][8] fragments of 16x16, mfma_f32_16x16x32_bf16, BK=64.
// LDS [idx][64k] bf16 rows with chunk-XOR swizzle (q ^= row&7): linear
// global_load_lds dest + pre-swizzled global src + swizzled ds_read_b128.
// b-fragment loaded inside the n-loop to cap live VGPRs.
// ---------------------------------------------------------------------------
template <int KPAD, int NH>
__global__ __launch_bounds__(256, 2) void gemm_mfma(
        const __hip_bfloat16* __restrict__ Xb, const __hip_bfloat16* __restrict__ Wt,
        const float* __restrict__ ASRC, const float* __restrict__ ADST,
        __hip_bfloat16* __restrict__ H, float* __restrict__ ES, float* __restrict__ ED) {
    __shared__ char As[128 * 128];                   // [128 rows][64 k] bf16
    __shared__ char Bs[256 * 128];                   // [256 cols][64 k] bf16
    __shared__ float red[2][128][2];                 // NH==1 cross-wave ES/ED

    const int t = threadIdx.x;
    const int wv = t >> 6, lane = t & 63;
    const int wr = wv >> 1, wc = wv & 1;
    const int r15 = lane & 15, hi = lane >> 4;
    const int n0 = blockIdx.x * 128;
    const int srow = lane >> 3;                      // staging: row-within-8
    const int sx = ((lane & 7) ^ srow) * 16;         // pre-swizzled source chunk
    constexpr int KB = KPAD * 2;                     // row bytes

    f32x4 acc[4][8];
#pragma unroll
    for (int m = 0; m < 4; m++)
#pragma unroll
        for (int n = 0; n < 8; n++) acc[m][n] = (f32x4){0.f, 0.f, 0.f, 0.f};

    for (int kt = 0; kt < KPAD / 64; kt++) {
        if (kt) __syncthreads();
        const int k0b = kt * 128;
        // ---- stage A: 16 x 1KB segments (4 per wave) ----
#pragma unroll
        for (int p = 0; p < 4; p++) {
            int i = wv * 4 + p;
            int gr = n0 + i * 8 + srow;
            if (gr > N_NODES_C - 1) gr = N_NODES_C - 1;
            gload_lds16((const char*)Xb + (size_t)gr * KB + k0b + sx, As + i * 1024);
        }
        // ---- stage B: 32 x 1KB segments (8 per wave) ----
#pragma unroll
        for (int p = 0; p < 8; p++) {
            int i = wv * 8 + p;
            int col = i * 8 + srow;
            gload_lds16((const char*)Wt + (size_t)col * KB + k0b + sx, Bs + i * 1024);
        }
        asm volatile("s_waitcnt vmcnt(0)" ::: "memory");
        __syncthreads();

        // ---- compute: 2 k-substeps of 32 ----
#pragma unroll
        for (int ks = 0; ks < 2; ks++) {
            const int cx = ((ks * 4 + hi) ^ (r15 & 7)) * 16;  // swizzled chunk byte
            short8v a[4];
#pragma unroll
            for (int m = 0; m < 4; m++)
                a[m] = *(const short8v*)(As + (wr * 64 + m * 16 + r15) * 128 + cx);
#pragma unroll
            for (int n = 0; n < 8; n++) {
                short8v b = *(const short8v*)(Bs + (wc * 128 + n * 16 + r15) * 128 + cx);
#pragma unroll
                for (int m = 0; m < 4; m++)
                    acc[m][n] = __builtin_amdgcn_mfma_f32_16x16x32_bf16(a[m], b, acc[m][n], 0, 0, 0);
            }
        }
    }

    // ---- epilogue: H (bf16) + attention dots ----
    float asv[8], adv[8];
#pragma unroll
    for (int n = 0; n < 8; n++) {
        int col = wc * 128 + n * 16 + r15;
        asv[n] = ASRC[col];
        adv[n] = ADST[col];
    }

#pragma unroll
    for (int m = 0; m < 4; m++) {
#pragma unroll
        for (int j = 0; j < 4; j++) {
            int lrow = wr * 64 + m * 16 + hi * 4 + j;
            int row = n0 + lrow;
            bool ok = row < N_NODES_C;
            if (ok) {
#pragma unroll
                for (int n = 0; n < 8; n++)
                    H[(size_t)row * KDIM + wc * 128 + n * 16 + r15] =
                        __float2bfloat16(acc[m][n][j]);
            }
            if (NH == 4) {
                float p0s = 0.f, p1s = 0.f, p0d = 0.f, p1d = 0.f;
#pragma unroll
                for (int n = 0; n < 4; n++) {
                    p0s = fmaf(acc[m][n][j], asv[n], p0s);
                    p0d = fmaf(acc[m][n][j], adv[n], p0d);
                    p1s = fmaf(acc[m][n + 4][j], asv[n + 4], p1s);
                    p1d = fmaf(acc[m][n + 4][j], adv[n + 4], p1d);
                }
#pragma unroll
                for (int s = 8; s; s >>= 1) {
                    p0s += __shfl_xor(p0s, s, 16);
                    p0d += __shfl_xor(p0d, s, 16);
                    p1s += __shfl_xor(p1s, s, 16);
                    p1d += __shfl_xor(p1d, s, 16);
                }
                if (r15 == 0 && ok) {
                    ES[row * 4 + wc * 2 + 0] = p0s;
                    ES[row * 4 + wc * 2 + 1] = p1s;
                    ED[row * 4 + wc * 2 + 0] = p0d;
                    ED[row * 4 + wc * 2 + 1] = p1d;
                }
            } else {
                float ps = 0.f, pd = 0.f;
#pragma unroll
                for (int n = 0; n < 8; n++) {
                    ps = fmaf(acc[m][n][j], asv[n], ps);
                    pd = fmaf(acc[m][n][j], adv[n], pd);
                }
#pragma unroll
                for (int s = 8; s; s >>= 1) {
                    ps += __shfl_xor(ps, s, 16);
                    pd += __shfl_xor(pd, s, 16);
                }
                if (r15 == 0) { red[0][lrow][wc] = ps; red[1][lrow][wc] = pd; }
            }
        }
    }
    if (NH == 1) {
        __syncthreads();
        if (t < 128) {
            int row = n0 + t;
            if (row < N_NODES_C) {
                ES[row] = red[0][t][0] + red[0][t][1];
                ED[row] = red[1][t][0] + red[1][t][1];
            }
        }
    }
}

// ---------------------------------------------------------------------------
// Edge-parallel logit precompute: E[slot][h] = leaky_relu(ES[src,h]+ED[dst,h])
// CSR-ordered output -> agg reads it contiguously (no dependent gathers).
// ---------------------------------------------------------------------------
template <int NH>
__global__ __launch_bounds__(256) void edge_e_k(
        const int* __restrict__ csr_src, const int* __restrict__ csr_dst,
        const float* __restrict__ ES, const float* __restrict__ ED,
        float* __restrict__ E) {
    int j = blockIdx.x * 256 + threadIdx.x;
    if (j >= E_TOT) return;
    int s = csr_src[j], d = csr_dst[j];
    if (NH == 4) {
        float4 es = *(const float4*)&ES[s * 4];
        float4 ed = *(const float4*)&ED[d * 4];
        float4 e;
        e.x = es.x + ed.x; e.x = (e.x > 0.f) ? e.x : 0.2f * e.x;
        e.y = es.y + ed.y; e.y = (e.y > 0.f) ? e.y : 0.2f * e.y;
        e.z = es.z + ed.z; e.z = (e.z > 0.f) ? e.z : 0.2f * e.z;
        e.w = es.w + ed.w; e.w = (e.w > 0.f) ? e.w : 0.2f * e.w;
        *(float4*)&E[j * 4] = e;
    } else {
        float e = ES[s] + ED[d];
        E[j] = (e > 0.f) ? e : 0.2f * e;
    }
}

// ---------------------------------------------------------------------------
// Per-dst softmax aggregation: 2 nodes per wave (32 lanes each), lane owns
// 8 channels (16B dwordx4 gathers). Logits precomputed & contiguous in E;
// 4-wide unroll keeps four independent H-row gathers in flight.
// ---------------------------------------------------------------------------
template <int NH, bool RELU>
__global__ __launch_bounds__(256) void agg_kernel(
        const __hip_bfloat16* __restrict__ H, const int* __restrict__ rowoff,
        const int* __restrict__ csr_src, const float* __restrict__ E,
        const float* __restrict__ bias, __hip_bfloat16* __restrict__ Out) {
    int node = blockIdx.x * 8 + (threadIdx.x >> 5);   // grid*8 == N exactly
    int l = threadIdx.x & 31;
    int c0 = l * 8;
    int head = (NH == 4) ? (l >> 3) : 0;
    int beg = rowoff[node], end = rowoff[node + 1];

    float m = -1e30f;
    for (int j = beg; j < end; j++) m = fmaxf(m, E[j * NH + head]);

    float s = 0.f;
    float a[8];
#pragma unroll
    for (int i = 0; i < 8; i++) a[i] = 0.f;
    const unsigned short* Hu = (const unsigned short*)H;

#define ACC8(v, p) \
    a[0] = fmaf(p, bflo(v.x), a[0]); a[1] = fmaf(p, bfhi(v.x), a[1]); \
    a[2] = fmaf(p, bflo(v.y), a[2]); a[3] = fmaf(p, bfhi(v.y), a[3]); \
    a[4] = fmaf(p, bflo(v.z), a[4]); a[5] = fmaf(p, bfhi(v.z), a[5]); \
    a[6] = fmaf(p, bflo(v.w), a[6]); a[7] = fmaf(p, bfhi(v.w), a[7]);

    int j = beg;
    for (; j + 4 <= end; j += 4) {
        int s0 = csr_src[j], s1 = csr_src[j + 1], s2 = csr_src[j + 2], s3 = csr_src[j + 3];
        float e0 = E[(j + 0) * NH + head], e1 = E[(j + 1) * NH + head];
        float e2 = E[(j + 2) * NH + head], e3 = E[(j + 3) * NH + head];
        uint4 v0 = *(const uint4*)(Hu + (size_t)s0 * KDIM + c0);
        uint4 v1 = *(const uint4*)(Hu + (size_t)s1 * KDIM + c0);
        uint4 v2 = *(const uint4*)(Hu + (size_t)s2 * KDIM + c0);
        uint4 v3 = *(const uint4*)(Hu + (size_t)s3 * KDIM + c0);
        float p0 = __expf(e0 - m), p1 = __expf(e1 - m);
        float p2 = __expf(e2 - m), p3 = __expf(e3 - m);
        s += p0 + p1 + p2 + p3;
        ACC8(v0, p0)
        ACC8(v1, p1)
        ACC8(v2, p2)
        ACC8(v3, p3)
    }
    for (; j < end; j++) {
        int s0 = csr_src[j];
        float e0 = E[j * NH + head];
        uint4 v0 = *(const uint4*)(Hu + (size_t)s0 * KDIM + c0);
        float p0 = __expf(e0 - m);
        s += p0;
        ACC8(v0, p0)
    }
#undef ACC8

    float inv = 1.f / s;
    float4 b0 = *(const float4*)&bias[c0];
    float4 b1 = *(const float4*)&bias[c0 + 4];
    float o[8];
    o[0] = fmaf(a[0], inv, b0.x); o[1] = fmaf(a[1], inv, b0.y);
    o[2] = fmaf(a[2], inv, b0.z); o[3] = fmaf(a[3], inv, b0.w);
    o[4] = fmaf(a[4], inv, b1.x); o[5] = fmaf(a[5], inv, b1.y);
    o[6] = fmaf(a[6], inv, b1.z); o[7] = fmaf(a[7], inv, b1.w);
    __hip_bfloat16 rb[8];
#pragma unroll
    for (int i = 0; i < 8; i++) {
        float v = RELU ? fmaxf(o[i], 0.f) : o[i];
        rb[i] = __float2bfloat16(v);
    }
    *(uint4*)&Out[(size_t)node * KDIM + c0] = *(uint4*)rb;
}

// ---------------------------------------------------------------------------
// Global max pool over graphs. 4 rows in flight (wave = row offset), uint2
// loads (4 bf16 channels/thread), LDS cross-wave combine.
// ---------------------------------------------------------------------------
__global__ __launch_bounds__(256) void pool_k(
        const __hip_bfloat16* __restrict__ O, const int* __restrict__ batch,
        float* __restrict__ out) {
    __shared__ int range[2];
    __shared__ float red[3][256];
    int g = blockIdx.x, k = threadIdx.x;
    if (k < 2) {
        int v = g + k;
        int lo = 0, hi = N_NODES_C;
        while (lo < hi) { int mid = (lo + hi) >> 1; if (batch[mid] < v) lo = mid + 1; else hi = mid; }
        range[k] = lo;
    }
    __syncthreads();
    int cg = k & 63;                 // channels cg*4 .. cg*4+3
    int ro = k >> 6;                 // wave = row offset
    float m0 = -INFINITY, m1 = -INFINITY, m2 = -INFINITY, m3 = -INFINITY;
    const unsigned short* Ou = (const unsigned short*)O;
    for (int i = range[0] + ro; i < range[1]; i += 4) {
        uint2 v = *(const uint2*)(Ou + (size_t)i * KDIM + cg * 4);
        m0 = fmaxf(m0, bflo(v.x)); m1 = fmaxf(m1, bfhi(v.x));
        m2 = fmaxf(m2, bflo(v.y)); m3 = fmaxf(m3, bfhi(v.y));
    }
    if (ro) {
        red[ro - 1][cg * 4 + 0] = m0; red[ro - 1][cg * 4 + 1] = m1;
        red[ro - 1][cg * 4 + 2] = m2; red[ro - 1][cg * 4 + 3] = m3;
    }
    __syncthreads();
    if (ro == 0) {
        m0 = fmaxf(fmaxf(m0, red[0][cg * 4 + 0]), fmaxf(red[1][cg * 4 + 0], red[2][cg * 4 + 0]));
        m1 = fmaxf(fmaxf(m1, red[0][cg * 4 + 1]), fmaxf(red[1][cg * 4 + 1], red[2][cg * 4 + 1]));
        m2 = fmaxf(fmaxf(m2, red[0][cg * 4 + 2]), fmaxf(red[1][cg * 4 + 2], red[2][cg * 4 + 2]));
        m3 = fmaxf(fmaxf(m3, red[0][cg * 4 + 3]), fmaxf(red[1][cg * 4 + 3], red[2][cg * 4 + 3]));
        float4 o = make_float4(m0, m1, m2, m3);
        *(float4*)&out[(size_t)g * KDIM + cg * 4] = o;
    }
}

// ---------------------------------------------------------------------------
extern "C" void kernel_launch(void* const* d_in, const int* in_sizes, int n_in,
                              void* d_out, int out_size, void* d_ws, size_t ws_size,
                              hipStream_t stream) {
    const float* x     = (const float*)d_in[0];
    const int*   ei    = (const int*)d_in[1];
    const int*   batch = (const int*)d_in[2];
    const float* W1  = (const float*)d_in[3];
    const float* as1 = (const float*)d_in[4];
    const float* ad1 = (const float*)d_in[5];
    const float* b1  = (const float*)d_in[6];
    const float* W2  = (const float*)d_in[7];
    const float* as2 = (const float*)d_in[8];
    const float* ad2 = (const float*)d_in[9];
    const float* b2  = (const float*)d_in[10];
    const float* W3  = (const float*)d_in[11];
    const float* as3 = (const float*)d_in[12];
    const float* ad3 = (const float*)d_in[13];
    const float* b3  = (const float*)d_in[14];
    float* out = (float*)d_out;

    // Workspace layout (~135 MB)
    char* p = (char*)d_ws;
    auto alloc = [&](size_t bytes) { char* r = p; p += (bytes + 255) & ~(size_t)255; return r; };
    __hip_bfloat16* Xb  = (__hip_bfloat16*)alloc((size_t)N_NODES_C * 64 * 2);
    __hip_bfloat16* Hb  = (__hip_bfloat16*)alloc((size_t)N_NODES_C * KDIM * 2);
    __hip_bfloat16* Nb  = (__hip_bfloat16*)alloc((size_t)N_NODES_C * KDIM * 2);
    __hip_bfloat16* Wt1 = (__hip_bfloat16*)alloc(256 * 64 * 2);
    __hip_bfloat16* Wt2 = (__hip_bfloat16*)alloc(256 * 256 * 2);
    __hip_bfloat16* Wt3 = (__hip_bfloat16*)alloc(256 * 256 * 2);
    float* ES     = (float*)alloc((size_t)N_NODES_C * 4 * 4);
    float* ED     = (float*)alloc((size_t)N_NODES_C * 4 * 4);
    float* Ecoef  = (float*)alloc((size_t)E_TOT * 4 * 4);
    int* deg      = (int*)alloc((N_NODES_C + 1) * 4);
    int* rowoff   = (int*)alloc((N_NODES_C + 1) * 4);
    int* cursor   = (int*)alloc(N_NODES_C * 4);
    int* csr      = (int*)alloc((size_t)E_TOT * 4 + 256);   // +pad
    int* csrd     = (int*)alloc((size_t)E_TOT * 4);
    int* partials = (int*)alloc(512 * 4);

    // --- input conversions ---
    conv_x_k<<<(N_NODES_C * 64 + 255) / 256, 256, 0, stream>>>(x, Xb);
    conv_wt_k<58, 64><<<64, 256, 0, stream>>>(W1, Wt1);
    conv_wt_k<256, 256><<<256, 256, 0, stream>>>(W2, Wt2);
    conv_wt_k<256, 256><<<256, 256, 0, stream>>>(W3, Wt3);

    // --- build CSR ---
    hipMemsetAsync(deg, 0, (N_NODES_C + 1) * 4, stream);
    hipMemsetAsync(cursor, 0, N_NODES_C * 4, stream);
    int egrid = (E_TOT + 255) / 256;
    count_deg_k<<<egrid, 256, 0, stream>>>(ei, deg);
    int nb = (N_NODES_C + 1 + 255) / 256;           // 391
    scan_chunk<<<nb, 256, 0, stream>>>(deg, rowoff, partials, N_NODES_C + 1);
    scan_partials<<<1, 512, 0, stream>>>(partials, nb);
    add_partials<<<nb, 256, 0, stream>>>(rowoff, partials, N_NODES_C + 1);
    scatter_k<<<egrid, 256, 0, stream>>>(ei, rowoff, cursor, csr, csrd);

    int ggrid = (N_NODES_C + 127) / 128;             // 782
    int agrid = N_NODES_C / 8;                       // 12500 (exact)
    // --- layer 1: 58(->64) -> 4x64, relu ---
    gemm_mfma<64, 4><<<ggrid, 256, 0, stream>>>(Xb, Wt1, as1, ad1, Hb, ES, ED);
    edge_e_k<4><<<egrid, 256, 0, stream>>>(csr, csrd, ES, ED, Ecoef);
    agg_kernel<4, true><<<agrid, 256, 0, stream>>>(Hb, rowoff, csr, Ecoef, b1, Nb);
    // --- layer 2: 256 -> 4x64, relu ---
    gemm_mfma<256, 4><<<ggrid, 256, 0, stream>>>(Nb, Wt2, as2, ad2, Hb, ES, ED);
    edge_e_k<4><<<egrid, 256, 0, stream>>>(csr, csrd, ES, ED, Ecoef);
    agg_kernel<4, true><<<agrid, 256, 0, stream>>>(Hb, rowoff, csr, Ecoef, b2, Nb);
    // --- layer 3: 256 -> 1x256, no relu ---
    gemm_mfma<256, 1><<<ggrid, 256, 0, stream>>>(Nb, Wt3, as3, ad3, Hb, ES, ED);
    edge_e_k<1><<<egrid, 256, 0, stream>>>(csr, csrd, ES, ED, Ecoef);
    agg_kernel<1, false><<<agrid, 256, 0, stream>>>(Hb, rowoff, csr, Ecoef, b3, Nb);
    // --- global max pool ---
    pool_k<<<N_GRAPHS_C, 256, 0, stream>>>(Nb, batch, out);
}